// Round 5
// baseline (877.238 us; speedup 1.0000x reference)
//
#include <hip/hip_runtime.h>

// GNN: 4x GraphSAGE(mean) + skip Linear + BN(1-3) + ReLU(1-3), fp32.
// N=50000 nodes, E=800000 edges, dims 128->256->128->64->40.
//
// Round 4 = round 3 resubmit (round 4 bench was an infra failure, no signal).
// GEMMs on split-bf16 MFMA (a = a_hi + a_lo, 3 MFMAs: Ah*Bh + Ah*Bl + Al*Bh,
// fp32 accum) -- fp32-VALU GEMM was stuck at 49 TF (VALUBusy 39%, occ 15%);
// MFMA effective ceiling ~830 TF.
//  - L1 (128->256): aggregate x first, ONE MFMA GEMM A=[agg|x], B=[Wl1;Wr1+Ws1]
//    with fused bias+relu+BN-stats epilogue.
//  - L2-4: MFMA GEMM Z = bn(h) @ [Wl | Wr+Ws]  (affine on A-load), then
//    combine: y = mean_nbrs(Zl[src]) + Zr + bias (+relu+stats).
//  - BN folded to per-column affine (a,b). bn_affine self-zeroes sums.
// MFMA tile: 128x128, BK=64, 4 waves x (64x64), frag-order LDS planes
// [kblock][row][8k], plane stride 2064B (bank-conflict-free reads+writes).

static constexpr int NN = 50000;
static constexpr int NE = 800000;

typedef __attribute__((ext_vector_type(8))) short short8;
typedef __attribute__((ext_vector_type(4))) float f32x4;

static constexpr int SK = 2064;           // LDS plane stride (bytes): 128*16 + 16
static constexpr int AH_OFF = 0;          // 8 planes * 2064 = 16512 B each
static constexpr int AL_OFF = 16512;
static constexpr int BH_OFF = 33024;
static constexpr int BL_OFF = 49536;      // total 66048 B

__device__ __forceinline__ unsigned short bf16rne(float x) {
  unsigned u = __float_as_uint(x);
  return (unsigned short)((u + 0x7FFFu + ((u >> 16) & 1u)) >> 16);
}
// split f into hi+lo bf16 (packed pair-wise into uints by caller order)
__device__ __forceinline__ void split2(float f0, float f1, unsigned& hi, unsigned& lo) {
  unsigned short h0 = bf16rne(f0), h1 = bf16rne(f1);
  float r0 = f0 - __uint_as_float(((unsigned)h0) << 16);
  float r1 = f1 - __uint_as_float(((unsigned)h1) << 16);
  unsigned short l0 = bf16rne(r0), l1 = bf16rne(r1);
  hi = (unsigned)h0 | ((unsigned)h1 << 16);
  lo = (unsigned)l0 | ((unsigned)l1 << 16);
}

__global__ void count_deg(const int* __restrict__ dst, int* __restrict__ cnt, int E) {
  int e = blockIdx.x * blockDim.x + threadIdx.x;
  if (e < E) atomicAdd(&cnt[dst[e]], 1);
}

__global__ __launch_bounds__(1024) void scan_block(const int* __restrict__ cnt,
                                                   int* __restrict__ excl,
                                                   int* __restrict__ btot, int n) {
  __shared__ int lds[1024];
  int i = blockIdx.x * 1024 + threadIdx.x;
  int v = (i < n) ? cnt[i] : 0;
  lds[threadIdx.x] = v;
  __syncthreads();
#pragma unroll
  for (int off = 1; off < 1024; off <<= 1) {
    int t = 0;
    if ((int)threadIdx.x >= off) t = lds[threadIdx.x - off];
    __syncthreads();
    lds[threadIdx.x] += t;
    __syncthreads();
  }
  if (i < n) excl[i] = lds[threadIdx.x] - v;
  if (threadIdx.x == 1023) btot[blockIdx.x] = lds[1023];
}

__global__ void scan_tops(int* __restrict__ btot, int nb) {
  int t = threadIdx.x;
  int v = (t < nb) ? btot[t] : 0;
  int own = v;
#pragma unroll
  for (int off = 1; off < 64; off <<= 1) {
    int u = __shfl_up(v, off);
    if (t >= off) v += u;
  }
  if (t < nb) btot[t] = v - own;
}

__global__ void finalize_csr(int* __restrict__ offs, const int* __restrict__ btot,
                             const int* __restrict__ cnt, int* __restrict__ cursor,
                             float* __restrict__ inv, int n) {
  int i = blockIdx.x * blockDim.x + threadIdx.x;
  if (i < n) {
    int o = offs[i] + btot[i >> 10];
    offs[i] = o;
    cursor[i] = o;
    int c = cnt[i];
    inv[i] = 1.0f / (float)(c > 0 ? c : 1);
  }
}

__global__ void fill_adj(const int* __restrict__ src, const int* __restrict__ dst,
                         int* __restrict__ cursor, int* __restrict__ adj, int E) {
  int e = blockIdx.x * blockDim.x + threadIdx.x;
  if (e < E) {
    int p = atomicAdd(&cursor[dst[e]], 1);
    adj[p] = src[e];
  }
}

// L1 pre-aggregation of x (D=128). Block 0 zeroes sums for L1 stats.
__global__ void aggregate1(const float* __restrict__ h, const int* __restrict__ adj,
                           const int* __restrict__ offs, const int* __restrict__ cnt,
                           const float* __restrict__ inv, float* __restrict__ agg,
                           float* __restrict__ sums) {
  const int D = 128;
  int n = blockIdx.x;
  int t = threadIdx.x;
  if (n == 0) {
    for (int j = t; j < 512; j += D) sums[j] = 0.f;
  }
  int off = offs[n];
  int deg = cnt[n];
  const float* __restrict__ hp = h + t;
  float s = 0.f;
  int i = 0;
  for (; i + 4 <= deg; i += 4) {
    int s0 = adj[off + i + 0];
    int s1 = adj[off + i + 1];
    int s2 = adj[off + i + 2];
    int s3 = adj[off + i + 3];
    float v0 = hp[(size_t)s0 * D];
    float v1 = hp[(size_t)s1 * D];
    float v2 = hp[(size_t)s2 * D];
    float v3 = hp[(size_t)s3 * D];
    s += (v0 + v1) + (v2 + v3);
  }
  for (; i < deg; ++i) s += hp[(size_t)adj[off + i] * D];
  agg[(size_t)n * D + t] = s * inv[n];
}

// Split-bf16 MFMA GEMM: C[N x Mp] = A @ B.
// TWO_A (L1): A = [A1 | A2] along K (K1,K2), B = [Wl ; Wr+Ws] stacked K, Mp=M.
// else:       A = A1 (affine a*h+b if AFFINE, ab[2*K1]), B = [Wl | Wr+Ws], Mp=2M.
// EPI: += (bl+bs), relu, column sum/sumsq into sums (L1 only).
template <int TWO_A, int AFFINE, int EPI>
__global__ __launch_bounds__(256) void gemm_mfma(
    const float* __restrict__ A1, const float* __restrict__ A2,
    const float* __restrict__ Wl, const float* __restrict__ Wr,
    const float* __restrict__ Wsk, const float* __restrict__ bl,
    const float* __restrict__ bs, const float* __restrict__ ab,
    float* __restrict__ Out, float* __restrict__ sums,
    int N, int K1, int K2, int M, int Mp) {
  __shared__ float4 smem4[66048 / 16];
  char* sm = (char*)smem4;

  const int tid = threadIdx.x;
  const int l = tid & 63;
  const int w = tid >> 6;
  const int wr = w >> 1, wc = w & 1;
  const int row0 = blockIdx.x * 128, col0 = blockIdx.y * 128;
  const int Ktot = K1 + K2;

  const f32x4 z4 = {0.f, 0.f, 0.f, 0.f};
  f32x4 acc[4][4];
#pragma unroll
  for (int m = 0; m < 4; ++m)
#pragma unroll
    for (int n = 0; n < 4; ++n) acc[m][n] = z4;

  for (int k0 = 0; k0 < Ktot; k0 += 64) {
    // ---- stage A (fp32 -> hi/lo bf16 planes) ----
    const float* __restrict__ Asrc = A1;
    int kl = k0, SA = K1;
    if (TWO_A && k0 >= K1) { Asrc = A2; kl = k0 - K1; SA = K2; }
#pragma unroll
    for (int u = 0; u < 8; ++u) {
      int i4 = u * 256 + tid;        // 0..2047
      int r = i4 >> 4;               // 0..127
      int kq = (i4 & 15) * 4;        // 0..60
      float4 av = make_float4(0.f, 0.f, 0.f, 0.f);
      int gr = row0 + r;
      if (gr < N) av = *(const float4*)&Asrc[(size_t)gr * SA + kl + kq];
      if (AFFINE) {
        float4 aa = *(const float4*)&ab[kl + kq];
        float4 bb = *(const float4*)&ab[K1 + kl + kq];
        av.x = fmaf(aa.x, av.x, bb.x);
        av.y = fmaf(aa.y, av.y, bb.y);
        av.z = fmaf(aa.z, av.z, bb.z);
        av.w = fmaf(aa.w, av.w, bb.w);
      }
      unsigned h0, l0, h1, l1;
      split2(av.x, av.y, h0, l0);
      split2(av.z, av.w, h1, l1);
      int byte_ = (kq >> 3) * SK + r * 16 + (kq & 7) * 2;
      *(uint2*)(sm + AH_OFF + byte_) = make_uint2(h0, h1);
      *(uint2*)(sm + AL_OFF + byte_) = make_uint2(l0, l1);
    }
    // ---- stage B (weights, k-strided loads -> k-contiguous planes) ----
    {
      int c = tid & 127;
      int kb0 = (tid >> 7) * 32;     // 0 or 32
      int gc = col0 + c;
#pragma unroll
      for (int g = 0; g < 8; ++g) {
        int kk = kb0 + g * 4;
        float f[4];
#pragma unroll
        for (int j = 0; j < 4; ++j) {
          int gk = k0 + kk + j;
          float v = 0.f;
          if (TWO_A) {
            if (gc < Mp)
              v = (gk < K1) ? Wl[(size_t)gk * M + gc]
                            : Wr[(size_t)(gk - K1) * M + gc] +
                              Wsk[(size_t)(gk - K1) * M + gc];
          } else {
            if (gc < Mp)
              v = (gc < M) ? Wl[(size_t)gk * M + gc]
                           : Wr[(size_t)gk * M + (gc - M)] +
                             Wsk[(size_t)gk * M + (gc - M)];
          }
          f[j] = v;
        }
        unsigned h0, l0, h1, l1;
        split2(f[0], f[1], h0, l0);
        split2(f[2], f[3], h1, l1);
        int byte_ = (kk >> 3) * SK + c * 16 + (kk & 7) * 2;
        *(uint2*)(sm + BH_OFF + byte_) = make_uint2(h0, h1);
        *(uint2*)(sm + BL_OFF + byte_) = make_uint2(l0, l1);
      }
    }
    __syncthreads();
    // ---- compute: 2 K-steps of 32 ----
#pragma unroll
    for (int s = 0; s < 2; ++s) {
      const int kbb = (s * 4 + (l >> 4)) * SK;
      short8 bh[4], blo[4];
#pragma unroll
      for (int n = 0; n < 4; ++n) {
        int off = kbb + (wc * 64 + n * 16 + (l & 15)) * 16;
        bh[n] = *(const short8*)(sm + BH_OFF + off);
        blo[n] = *(const short8*)(sm + BL_OFF + off);
      }
#pragma unroll
      for (int m = 0; m < 4; ++m) {
        int offa = kbb + (wr * 64 + m * 16 + (l & 15)) * 16;
        short8 ah = *(const short8*)(sm + AH_OFF + offa);
        short8 al = *(const short8*)(sm + AL_OFF + offa);
#pragma unroll
        for (int n = 0; n < 4; ++n) {
          acc[m][n] = __builtin_amdgcn_mfma_f32_16x16x32_bf16(ah, bh[n], acc[m][n], 0, 0, 0);
          acc[m][n] = __builtin_amdgcn_mfma_f32_16x16x32_bf16(ah, blo[n], acc[m][n], 0, 0, 0);
          acc[m][n] = __builtin_amdgcn_mfma_f32_16x16x32_bf16(al, bh[n], acc[m][n], 0, 0, 0);
        }
      }
    }
    __syncthreads();
  }

  // ---- epilogue: D layout col = l&15, row = (l>>4)*4 + i ----
  const int lr = (l >> 4) * 4;
  const int lc = l & 15;
  float cs[4] = {0.f, 0.f, 0.f, 0.f}, cq[4] = {0.f, 0.f, 0.f, 0.f};
#pragma unroll
  for (int n = 0; n < 4; ++n) {
    int col = col0 + wc * 64 + n * 16 + lc;
    bool cok = col < Mp;
    float bias = 0.f;
    if (EPI) bias = cok ? (bl[col] + bs[col]) : 0.f;
#pragma unroll
    for (int m = 0; m < 4; ++m) {
#pragma unroll
      for (int i = 0; i < 4; ++i) {
        int row = row0 + wr * 64 + m * 16 + lr + i;
        float v = acc[m][n][i];
        if (EPI) {
          v += bias;
          v = fmaxf(v, 0.f);
        }
        if (cok && row < N) {
          Out[(size_t)row * Mp + col] = v;
          if (EPI) {
            cs[n] += v;
            cq[n] += v * v;
          }
        }
      }
    }
  }

  if (EPI) {
    // reduce column stats: [128 cols][8 slots] x2 in reused LDS
    float* st = (float*)sm;
    int slot = wr * 4 + (l >> 4);
#pragma unroll
    for (int n = 0; n < 4; ++n) {
      int c = wc * 64 + n * 16 + lc;
      st[c * 8 + slot] = cs[n];
      st[1024 + c * 8 + slot] = cq[n];
    }
    __syncthreads();
    if (tid < 128) {
      float s1 = 0.f, s2 = 0.f;
#pragma unroll
      for (int t2 = 0; t2 < 8; ++t2) {
        s1 += st[tid * 8 + t2];
        s2 += st[1024 + tid * 8 + t2];
      }
      int c = col0 + tid;
      if (c < Mp) {
        atomicAdd(&sums[c], s1);
        atomicAdd(&sums[Mp + c], s2);
      }
    }
  }
}

// y[n][c] = mean_nbrs(Zl[src][c]) + Zr[n][c] + bl[c]+bs[c]; relu/stats opt.
// Z rows are [Zl(M) | Zr(M)], stride 2M. DPAD = M padded to wave multiple.
template <int DPAD, int LOGD, int M, int RELU, int STATS>
__global__ __launch_bounds__(256) void combine(
    const float* __restrict__ Z, const int* __restrict__ adj,
    const int* __restrict__ offs, const int* __restrict__ cnt,
    const float* __restrict__ inv, const float* __restrict__ bl,
    const float* __restrict__ bs, float* __restrict__ out,
    float* __restrict__ sums, int N) {
  constexpr int S = 256 / DPAD;
  constexpr int Mp = 2 * M;
  const int tid = threadIdx.x;
  const int c = tid & (DPAD - 1);
  const int sub = tid >> LOGD;
  const bool act = (c < M);
  const float bias = act ? (bl[c] + bs[c]) : 0.f;
  float cs = 0.f, cq = 0.f;
  const float* __restrict__ Zc = Z + c;
  for (int n = blockIdx.x * S + sub; n < N; n += gridDim.x * S) {
    if (act) {
      int off = offs[n], deg = cnt[n];
      float s = 0.f;
      int i = 0;
      for (; i + 4 <= deg; i += 4) {
        int s0 = adj[off + i + 0];
        int s1 = adj[off + i + 1];
        int s2 = adj[off + i + 2];
        int s3 = adj[off + i + 3];
        float v0 = Zc[(size_t)s0 * Mp];
        float v1 = Zc[(size_t)s1 * Mp];
        float v2 = Zc[(size_t)s2 * Mp];
        float v3 = Zc[(size_t)s3 * Mp];
        s += (v0 + v1) + (v2 + v3);
      }
      for (; i < deg; ++i) s += Zc[(size_t)adj[off + i] * Mp];
      float y = fmaf(s, inv[n], Z[(size_t)n * Mp + M + c] + bias);
      if (RELU) y = fmaxf(y, 0.f);
      out[(size_t)n * M + c] = y;
      if (STATS) { cs += y; cq += y * y; }
    }
  }
  if (STATS) {
    __shared__ float red[512];
    red[tid] = cs;
    red[256 + tid] = cq;
    __syncthreads();
    if (sub == 0 && act) {
#pragma unroll
      for (int s2 = 1; s2 < S; ++s2) {
        cs += red[s2 * DPAD + c];
        cq += red[256 + s2 * DPAD + c];
      }
      atomicAdd(&sums[c], cs);
      atomicAdd(&sums[M + c], cq);
    }
  }
}

__global__ void bn_affine(float* __restrict__ sums, const float* __restrict__ g,
                          const float* __restrict__ be, float* __restrict__ ab,
                          int M, float invN) {
  int j = threadIdx.x;
  if (j < M) {
    float s1 = sums[j], s2 = sums[M + j];
    float mu = s1 * invN;
    float var = fmaf(-mu, mu, s2 * invN);
    float a = g[j] / sqrtf(var + 1e-5f);
    ab[j] = a;
    ab[M + j] = fmaf(-mu, a, be[j]);
    sums[j] = 0.f;       // ready for next layer's stats
    sums[M + j] = 0.f;
  }
}

extern "C" void kernel_launch(void* const* d_in, const int* in_sizes, int n_in,
                              void* d_out, int out_size, void* d_ws, size_t ws_size,
                              hipStream_t stream) {
  const int N = NN, E = NE;
  const float* x = (const float*)d_in[0];
  const int* ei = (const int*)d_in[1];
  const int* srcs = ei;
  const int* dsts = ei + E;

  const float* Wl1 = (const float*)d_in[2];
  const float* bl1 = (const float*)d_in[3];
  const float* Wr1 = (const float*)d_in[4];
  const float* Ws1 = (const float*)d_in[5];
  const float* bs1 = (const float*)d_in[6];
  const float* g1  = (const float*)d_in[7];
  const float* be1 = (const float*)d_in[8];
  const float* Wl2 = (const float*)d_in[9];
  const float* bl2 = (const float*)d_in[10];
  const float* Wr2 = (const float*)d_in[11];
  const float* Ws2 = (const float*)d_in[12];
  const float* bs2 = (const float*)d_in[13];
  const float* g2  = (const float*)d_in[14];
  const float* be2 = (const float*)d_in[15];
  const float* Wl3 = (const float*)d_in[16];
  const float* bl3 = (const float*)d_in[17];
  const float* Wr3 = (const float*)d_in[18];
  const float* Ws3 = (const float*)d_in[19];
  const float* bs3 = (const float*)d_in[20];
  const float* g3  = (const float*)d_in[21];
  const float* be3 = (const float*)d_in[22];
  const float* Wl4 = (const float*)d_in[23];
  const float* bl4 = (const float*)d_in[24];
  const float* Wr4 = (const float*)d_in[25];
  const float* Ws4 = (const float*)d_in[26];
  const float* bs4 = (const float*)d_in[27];

  // workspace (~132 MB)
  float* ws = (float*)d_ws;
  float* Zbuf = ws;                            // N*256 (L1: agg uses N*128)
  float* hA   = Zbuf + (size_t)N * 256;        // N*256
  float* hB   = hA + (size_t)N * 256;          // N*128 (hC aliases it)
  float* sums = hB + (size_t)N * 128;          // 512
  float* ab   = sums + 512;                    // 512
  float* invc = ab + 512;                      // N
  int* cnt    = (int*)(invc + N);              // N
  int* offs   = cnt + N;                       // N
  int* cursor = offs + N;                      // N
  int* btot   = cursor + N;                    // 64
  int* adj    = btot + 64;                     // E
  float* hC = hB;

  hipMemsetAsync(cnt, 0, sizeof(int) * N, stream);
  int eb = (E + 255) / 256;
  int nb = (N + 1023) / 1024;  // 49
  count_deg<<<eb, 256, 0, stream>>>(dsts, cnt, E);
  scan_block<<<nb, 1024, 0, stream>>>(cnt, offs, btot, N);
  scan_tops<<<1, 64, 0, stream>>>(btot, nb);
  finalize_csr<<<(N + 255) / 256, 256, 0, stream>>>(offs, btot, cnt, cursor, invc, N);
  fill_adj<<<eb, 256, 0, stream>>>(srcs, dsts, cursor, adj, E);

  const int RB = (N + 127) / 128;  // 391
  const float invN = 1.0f / (float)N;
  float* agg = Zbuf;

  // L1: aggregate x, then [agg|x] @ [Wl1 ; Wr1+Ws1] + bias, relu, stats -> hA
  aggregate1<<<N, 128, 0, stream>>>(x, adj, offs, cnt, invc, agg, sums);
  gemm_mfma<1, 0, 1><<<dim3(RB, 2), 256, 0, stream>>>(
      agg, x, Wl1, Wr1, Ws1, bl1, bs1, nullptr, hA, sums, N, 128, 128, 256, 256);
  bn_affine<<<1, 256, 0, stream>>>(sums, g1, be1, ab, 256, invN);

  // L2: Z = bn1(hA) @ [Wl2 | Wr2+Ws2]; combine -> hB (relu+stats)
  gemm_mfma<0, 1, 0><<<dim3(RB, 2), 256, 0, stream>>>(
      hA, nullptr, Wl2, Wr2, Ws2, nullptr, nullptr, ab, Zbuf, nullptr, N, 256, 0, 128, 256);
  combine<128, 7, 128, 1, 1><<<2048, 256, 0, stream>>>(
      Zbuf, adj, offs, cnt, invc, bl2, bs2, hB, sums, N);
  bn_affine<<<1, 128, 0, stream>>>(sums, g2, be2, ab, 128, invN);

  // L3: Z = bn2(hB) @ [Wl3 | Wr3+Ws3]; combine -> hC (relu+stats)
  gemm_mfma<0, 1, 0><<<dim3(RB, 1), 256, 0, stream>>>(
      hB, nullptr, Wl3, Wr3, Ws3, nullptr, nullptr, ab, Zbuf, nullptr, N, 128, 0, 64, 128);
  combine<64, 6, 64, 1, 1><<<2048, 256, 0, stream>>>(
      Zbuf, adj, offs, cnt, invc, bl3, bs3, hC, sums, N);
  bn_affine<<<1, 64, 0, stream>>>(sums, g3, be3, ab, 64, invN);

  // L4: Z = bn3(hC) @ [Wl4 | Wr4+Ws4]; combine -> d_out (no relu/stats)
  gemm_mfma<0, 1, 0><<<dim3(RB, 1), 256, 0, stream>>>(
      hC, nullptr, Wl4, Wr4, Ws4, nullptr, nullptr, ab, Zbuf, nullptr, N, 64, 0, 40, 80);
  combine<64, 6, 40, 0, 0><<<2048, 256, 0, stream>>>(
      Zbuf, adj, offs, cnt, invc, bl4, bs4, (float*)d_out, nullptr, N);
}

// Round 6
// 661.471 us; speedup vs baseline: 1.3262x; 1.3262x over previous
//
#include <hip/hip_runtime.h>

// GNN: 4x GraphSAGE(mean) + skip Linear + BN(1-3) + ReLU(1-3), fp32.
// N=50000 nodes, E=800000 edges, dims 128->256->128->64->40.
//
// Round 6: MFMA GEMM restructured after r5 counters (MfmaUtil 4%, occ 8.5%):
//  - BN folded into WEIGHTS: bn(h)@W = h@(diag(a)W) + b@W. Affine gone from
//    GEMM; b@W becomes bias_all/bias_deg handled in combine (deg-gated, exact).
//  - All GEMM A-operands pre-packed bf16 hi/lo in MFMA fragment-planar layout
//    P[kb][sel][row][8k] (16B chunks), written by producers directly.
//  - Weights packed once per layer by prep_w (after bn_affine), zero-padded.
//  - gemm_pk: NO LDS, NO barriers, NO splits. Per K-32 step: 16 independent
//    dwordx4 frag loads (L2/L3-resident) + 48 MFMAs (split-bf16: hh+hl+lh).
// Numerics of split-bf16 + fragment maps verified r5 (absmax == fp32 rounds).

static constexpr int NN = 50000;
static constexpr int NE = 800000;
static constexpr int NP = 50048;   // rows padded to 128

typedef __attribute__((ext_vector_type(8))) short short8;
typedef __attribute__((ext_vector_type(4))) float f32x4;

__device__ __forceinline__ unsigned short bf16rne(float x) {
  unsigned u = __float_as_uint(x);
  return (unsigned short)((u + 0x7FFFu + ((u >> 16) & 1u)) >> 16);
}
__device__ __forceinline__ float bf2f(unsigned short h) {
  return __uint_as_float(((unsigned)h) << 16);
}

// ---------------- CSR build ----------------
__global__ void count_deg(const int* __restrict__ dst, int* __restrict__ cnt, int E) {
  int e = blockIdx.x * blockDim.x + threadIdx.x;
  if (e < E) atomicAdd(&cnt[dst[e]], 1);
}

__global__ __launch_bounds__(1024) void scan_block(const int* __restrict__ cnt,
                                                   int* __restrict__ excl,
                                                   int* __restrict__ btot, int n) {
  __shared__ int lds[1024];
  int i = blockIdx.x * 1024 + threadIdx.x;
  int v = (i < n) ? cnt[i] : 0;
  lds[threadIdx.x] = v;
  __syncthreads();
#pragma unroll
  for (int off = 1; off < 1024; off <<= 1) {
    int t = 0;
    if ((int)threadIdx.x >= off) t = lds[threadIdx.x - off];
    __syncthreads();
    lds[threadIdx.x] += t;
    __syncthreads();
  }
  if (i < n) excl[i] = lds[threadIdx.x] - v;
  if (threadIdx.x == 1023) btot[blockIdx.x] = lds[1023];
}

__global__ void scan_tops(int* __restrict__ btot, int nb) {
  int t = threadIdx.x;
  int v = (t < nb) ? btot[t] : 0;
  int own = v;
#pragma unroll
  for (int off = 1; off < 64; off <<= 1) {
    int u = __shfl_up(v, off);
    if (t >= off) v += u;
  }
  if (t < nb) btot[t] = v - own;
}

__global__ void finalize_csr(int* __restrict__ offs, const int* __restrict__ btot,
                             const int* __restrict__ cnt, int* __restrict__ cursor,
                             float* __restrict__ inv, int n) {
  int i = blockIdx.x * blockDim.x + threadIdx.x;
  if (i < n) {
    int o = offs[i] + btot[i >> 10];
    offs[i] = o;
    cursor[i] = o;
    int c = cnt[i];
    inv[i] = 1.0f / (float)(c > 0 ? c : 1);
  }
}

__global__ void fill_adj(const int* __restrict__ src, const int* __restrict__ dst,
                         int* __restrict__ cursor, int* __restrict__ adj, int E) {
  int e = blockIdx.x * blockDim.x + threadIdx.x;
  if (e < E) {
    int p = atomicAdd(&cursor[dst[e]], 1);
    adj[p] = src[e];
  }
}

// ---------------- packing ----------------
// x (N x 128) -> packed fragment-planar hi/lo. Rows N..NP-1 zero-filled.
__global__ void pack_x(const float* __restrict__ x, ushort* __restrict__ xP, int N) {
  int gid = blockIdx.x * 256 + threadIdx.x;
  int row = gid >> 4, kb = gid & 15;
  if (row >= NP) return;
  float v[8];
  if (row < N) {
    float4 a = *(const float4*)&x[(size_t)row * 128 + kb * 8];
    float4 b = *(const float4*)&x[(size_t)row * 128 + kb * 8 + 4];
    v[0]=a.x; v[1]=a.y; v[2]=a.z; v[3]=a.w; v[4]=b.x; v[5]=b.y; v[6]=b.z; v[7]=b.w;
  } else {
#pragma unroll
    for (int j = 0; j < 8; ++j) v[j] = 0.f;
  }
  short8 H, L;
#pragma unroll
  for (int j = 0; j < 8; ++j) {
    unsigned short h = bf16rne(v[j]);
    H[j] = (short)h;
    L[j] = (short)bf16rne(v[j] - bf2f(h));
  }
  *(short8*)&xP[((size_t)(kb * 2) * NP + row) * 8] = H;
  *(short8*)&xP[((size_t)(kb * 2 + 1) * NP + row) * 8] = L;
}

// Pack weights in B-fragment layout, with optional BN fold (w *= a[k]).
// L1V=1: B = [Wl ; Wr+Ws] stacked along K (K1 boundary), no scale.
// L1V=0: B cols = [diag(a)Wl | diag(a)(Wr+Ws)], a = ab[0..K).
template <int L1V>
__global__ void prep_w(const float* __restrict__ Wl, const float* __restrict__ Wr,
                       const float* __restrict__ Wsk, const float* __restrict__ ab,
                       ushort* __restrict__ Wp, int K, int K1, int M, int Mp, int Mpad) {
  int gid = blockIdx.x * 256 + threadIdx.x;
  int col = gid % Mpad, kb = gid / Mpad;
  if (kb >= (K >> 3)) return;
  short8 H, L;
#pragma unroll
  for (int j = 0; j < 8; ++j) {
    int k = kb * 8 + j;
    float v = 0.f;
    if (col < Mp) {
      if (L1V) {
        v = (k < K1) ? Wl[(size_t)k * M + col]
                     : Wr[(size_t)(k - K1) * M + col] + Wsk[(size_t)(k - K1) * M + col];
      } else {
        float w = (col < M) ? Wl[(size_t)k * M + col]
                            : Wr[(size_t)k * M + (col - M)] + Wsk[(size_t)k * M + (col - M)];
        v = ab[k] * w;
      }
    }
    unsigned short h = bf16rne(v);
    H[j] = (short)h;
    L[j] = (short)bf16rne(v - bf2f(h));
  }
  *(short8*)&Wp[((size_t)(kb * 2) * Mpad + col) * 8] = H;
  *(short8*)&Wp[((size_t)(kb * 2 + 1) * Mpad + col) * 8] = L;
}

// bias_all[c] = bl+bs+sum_k b[k](Wr+Ws)[k][c]; bias_deg[c] = sum_k b[k]Wl[k][c]
__global__ void prep_bias(const float* __restrict__ Wl, const float* __restrict__ Wr,
                          const float* __restrict__ Wsk, const float* __restrict__ bl,
                          const float* __restrict__ bs, const float* __restrict__ ab,
                          float* __restrict__ bias2, int K, int M) {
  int c = blockIdx.x;
  int k = threadIdx.x;
  float va = 0.f, vd = 0.f;
  if (k < K) {
    float b = ab[K + k];
    vd = b * Wl[(size_t)k * M + c];
    va = b * (Wr[(size_t)k * M + c] + Wsk[(size_t)k * M + c]);
  }
  __shared__ float r[512];
  r[k] = va;
  r[256 + k] = vd;
  __syncthreads();
  for (int off = 128; off > 0; off >>= 1) {
    if (k < off) {
      r[k] += r[k + off];
      r[256 + k] += r[256 + k + off];
    }
    __syncthreads();
  }
  if (k == 0) {
    bias2[c] = bl[c] + bs[c] + r[0];
    bias2[M + c] = r[256];
  }
}

// ---------------- aggregation (L1) ----------------
// mean of x over incoming nbrs, written PACKED. grid = NP; rows>=N -> zeros.
__global__ void aggregate1(const float* __restrict__ h, const int* __restrict__ adj,
                           const int* __restrict__ offs, const int* __restrict__ cnt,
                           const float* __restrict__ inv, ushort* __restrict__ aggP,
                           float* __restrict__ sums, int N) {
  const int D = 128;
  int n = blockIdx.x;
  int t = threadIdx.x;
  if (n == 0) {
    for (int j = t; j < 512; j += D) sums[j] = 0.f;
  }
  float m = 0.f;
  if (n < N) {
    int off = offs[n];
    int deg = cnt[n];
    const float* __restrict__ hp = h + t;
    float s = 0.f;
    int i = 0;
    for (; i + 4 <= deg; i += 4) {
      int s0 = adj[off + i + 0];
      int s1 = adj[off + i + 1];
      int s2 = adj[off + i + 2];
      int s3 = adj[off + i + 3];
      float v0 = hp[(size_t)s0 * D];
      float v1 = hp[(size_t)s1 * D];
      float v2 = hp[(size_t)s2 * D];
      float v3 = hp[(size_t)s3 * D];
      s += (v0 + v1) + (v2 + v3);
    }
    for (; i < deg; ++i) s += hp[(size_t)adj[off + i] * D];
    m = s * inv[n];
  }
  unsigned short hh = bf16rne(m);
  unsigned short ll = bf16rne(m - bf2f(hh));
  size_t base = ((size_t)((t >> 3) * 2) * NP + n) * 8 + (t & 7);
  aggP[base] = hh;
  aggP[base + (size_t)NP * 8] = ll;
}

// ---------------- MFMA GEMM (no LDS, no barriers) ----------------
// C[N x Mp] = A @ B, A packed (TWO_A: [A1|A2] along K at KT1), B packed.
// EPI=1 (L1): +bias(bl+bs), relu, BN stats, PACKED output.
// EPI=0: raw fp32 Z out (row stride Mp).
template <int TWO_A, int EPI, int NK32, int KT1>
__global__ __launch_bounds__(256) void gemm_pk(
    const ushort* __restrict__ A1, const ushort* __restrict__ A2,
    const ushort* __restrict__ B, const float* __restrict__ bl,
    const float* __restrict__ bs, float* __restrict__ OutF,
    ushort* __restrict__ OutP, float* __restrict__ sums,
    int N, int Mp, int Mpad) {
  const int tid = threadIdx.x;
  const int l = tid & 63;
  const int w = tid >> 6;
  const int wr = w >> 1, wc = w & 1;
  const int l16 = l & 15, lh = l >> 4;
  const int row0 = blockIdx.x * 128, col0 = blockIdx.y * 128;

  const f32x4 z4 = {0.f, 0.f, 0.f, 0.f};
  f32x4 acc[4][4];
#pragma unroll
  for (int m = 0; m < 4; ++m)
#pragma unroll
    for (int n = 0; n < 4; ++n) acc[m][n] = z4;

  const int arow = row0 + wr * 64 + l16;
  const int bcol = col0 + wc * 64 + l16;

#pragma unroll 2
  for (int it = 0; it < NK32; ++it) {
    const int kbase = it * 32;
    const ushort* Ap = A1;
    int kloc = kbase;
    if (TWO_A && kbase >= KT1) { Ap = A2; kloc = kbase - KT1; }
    const int akb = (kloc >> 3) + lh;
    const int bkb = (kbase >> 3) + lh;
    const ushort* a_hi = Ap + ((size_t)(akb * 2) * NP + arow) * 8;
    const ushort* a_lo = a_hi + (size_t)NP * 8;
    const ushort* b_hi = B + ((size_t)(bkb * 2) * Mpad + bcol) * 8;
    const ushort* b_lo = b_hi + (size_t)Mpad * 8;

    short8 ah[4], al[4], bh[4], blo[4];
#pragma unroll
    for (int m = 0; m < 4; ++m) {
      ah[m] = *(const short8*)(a_hi + m * 128);
      al[m] = *(const short8*)(a_lo + m * 128);
    }
#pragma unroll
    for (int n = 0; n < 4; ++n) {
      bh[n] = *(const short8*)(b_hi + n * 128);
      blo[n] = *(const short8*)(b_lo + n * 128);
    }
#pragma unroll
    for (int m = 0; m < 4; ++m)
#pragma unroll
      for (int n = 0; n < 4; ++n) {
        acc[m][n] = __builtin_amdgcn_mfma_f32_16x16x32_bf16(ah[m], bh[n], acc[m][n], 0, 0, 0);
        acc[m][n] = __builtin_amdgcn_mfma_f32_16x16x32_bf16(ah[m], blo[n], acc[m][n], 0, 0, 0);
        acc[m][n] = __builtin_amdgcn_mfma_f32_16x16x32_bf16(al[m], bh[n], acc[m][n], 0, 0, 0);
      }
  }

  const int lr = lh * 4;
  if (EPI) {
    __shared__ float st[2048];
    float cs[4] = {0.f, 0.f, 0.f, 0.f}, cq[4] = {0.f, 0.f, 0.f, 0.f};
#pragma unroll
    for (int n = 0; n < 4; ++n) {
      int col = col0 + wc * 64 + n * 16 + l16;
      bool cok = col < Mp;
      float bias = cok ? (bl[col] + bs[col]) : 0.f;
      int cb = col >> 3, ch = col & 7;
      size_t hbase = ((size_t)(cb * 2) * NP) * 8 + ch;
      size_t lbase = hbase + (size_t)NP * 8;
#pragma unroll
      for (int m = 0; m < 4; ++m)
#pragma unroll
        for (int i = 0; i < 4; ++i) {
          int row = row0 + wr * 64 + m * 16 + lr + i;
          float v = acc[m][n][i] + bias;
          v = fmaxf(v, 0.f);
          if (cok && row < N) {
            unsigned short hh = bf16rne(v);
            OutP[hbase + (size_t)row * 8] = hh;
            OutP[lbase + (size_t)row * 8] = bf16rne(v - bf2f(hh));
            cs[n] += v;
            cq[n] += v * v;
          }
        }
    }
    int slot = wr * 4 + lh;
#pragma unroll
    for (int n = 0; n < 4; ++n) {
      int c = wc * 64 + n * 16 + l16;
      st[c * 8 + slot] = cs[n];
      st[1024 + c * 8 + slot] = cq[n];
    }
    __syncthreads();
    if (tid < 128) {
      float s1 = 0.f, s2 = 0.f;
#pragma unroll
      for (int t2 = 0; t2 < 8; ++t2) {
        s1 += st[tid * 8 + t2];
        s2 += st[1024 + tid * 8 + t2];
      }
      int c = col0 + tid;
      if (c < Mp) {
        atomicAdd(&sums[c], s1);
        atomicAdd(&sums[Mp + c], s2);
      }
    }
  } else {
#pragma unroll
    for (int n = 0; n < 4; ++n) {
      int col = col0 + wc * 64 + n * 16 + l16;
      if (col >= Mp) continue;
#pragma unroll
      for (int m = 0; m < 4; ++m)
#pragma unroll
        for (int i = 0; i < 4; ++i) {
          int row = row0 + wr * 64 + m * 16 + lr + i;
          if (row < N) OutF[(size_t)row * Mp + col] = acc[m][n][i];
        }
    }
  }
}

// ---------------- combine (L2-4) ----------------
// y = mean_nbrs(Zl[src]) + Zr + bias_all + (deg>0 ? bias_deg : 0); relu/stats.
// PACK=1: write packed hi/lo fragment-planar; else fp32 out (row stride M).
template <int DPAD, int LOGD, int M, int RELU, int STATS, int PACK>
__global__ __launch_bounds__(256) void combine(
    const float* __restrict__ Z, const int* __restrict__ adj,
    const int* __restrict__ offs, const int* __restrict__ cnt,
    const float* __restrict__ inv, const float* __restrict__ bias2,
    float* __restrict__ outF, ushort* __restrict__ outP,
    float* __restrict__ sums, int N) {
  constexpr int S = 256 / DPAD;
  constexpr int Mp = 2 * M;
  const int tid = threadIdx.x;
  const int c = tid & (DPAD - 1);
  const int sub = tid >> LOGD;
  const bool act = (c < M);
  const float b_all = act ? bias2[c] : 0.f;
  const float b_deg = act ? bias2[M + c] : 0.f;
  float cs = 0.f, cq = 0.f;
  const float* __restrict__ Zc = Z + c;
  for (int n = blockIdx.x * S + sub; n < N; n += gridDim.x * S) {
    if (act) {
      int off = offs[n], deg = cnt[n];
      float s = 0.f;
      int i = 0;
      for (; i + 4 <= deg; i += 4) {
        int s0 = adj[off + i + 0];
        int s1 = adj[off + i + 1];
        int s2 = adj[off + i + 2];
        int s3 = adj[off + i + 3];
        float v0 = Zc[(size_t)s0 * Mp];
        float v1 = Zc[(size_t)s1 * Mp];
        float v2 = Zc[(size_t)s2 * Mp];
        float v3 = Zc[(size_t)s3 * Mp];
        s += (v0 + v1) + (v2 + v3);
      }
      for (; i < deg; ++i) s += Zc[(size_t)adj[off + i] * Mp];
      float y = fmaf(s, inv[n], Z[(size_t)n * Mp + M + c] + b_all);
      if (deg > 0) y += b_deg;
      if (RELU) y = fmaxf(y, 0.f);
      if (PACK) {
        unsigned short hh = bf16rne(y);
        size_t base = ((size_t)((c >> 3) * 2) * NP + n) * 8 + (c & 7);
        outP[base] = hh;
        outP[base + (size_t)NP * 8] = bf16rne(y - bf2f(hh));
      } else {
        outF[(size_t)n * M + c] = y;
      }
      if (STATS) { cs += y; cq += y * y; }
    }
  }
  if (STATS) {
    __shared__ float red[512];
    red[tid] = cs;
    red[256 + tid] = cq;
    __syncthreads();
    if (sub == 0 && act) {
#pragma unroll
      for (int s2 = 1; s2 < S; ++s2) {
        cs += red[s2 * DPAD + c];
        cq += red[256 + s2 * DPAD + c];
      }
      atomicAdd(&sums[c], cs);
      atomicAdd(&sums[M + c], cq);
    }
  }
}

__global__ void bn_affine(float* __restrict__ sums, const float* __restrict__ g,
                          const float* __restrict__ be, float* __restrict__ ab,
                          int M, float invN) {
  int j = threadIdx.x;
  if (j < M) {
    float s1 = sums[j], s2 = sums[M + j];
    float mu = s1 * invN;
    float var = fmaf(-mu, mu, s2 * invN);
    float a = g[j] / sqrtf(var + 1e-5f);
    ab[j] = a;
    ab[M + j] = fmaf(-mu, a, be[j]);
    sums[j] = 0.f;
    sums[M + j] = 0.f;
  }
}

extern "C" void kernel_launch(void* const* d_in, const int* in_sizes, int n_in,
                              void* d_out, int out_size, void* d_ws, size_t ws_size,
                              hipStream_t stream) {
  const int N = NN, E = NE;
  const float* x = (const float*)d_in[0];
  const int* ei = (const int*)d_in[1];
  const int* srcs = ei;
  const int* dsts = ei + E;

  const float* Wl1 = (const float*)d_in[2];
  const float* bl1 = (const float*)d_in[3];
  const float* Wr1 = (const float*)d_in[4];
  const float* Ws1 = (const float*)d_in[5];
  const float* bs1 = (const float*)d_in[6];
  const float* g1  = (const float*)d_in[7];
  const float* be1 = (const float*)d_in[8];
  const float* Wl2 = (const float*)d_in[9];
  const float* bl2 = (const float*)d_in[10];
  const float* Wr2 = (const float*)d_in[11];
  const float* Ws2 = (const float*)d_in[12];
  const float* bs2 = (const float*)d_in[13];
  const float* g2  = (const float*)d_in[14];
  const float* be2 = (const float*)d_in[15];
  const float* Wl3 = (const float*)d_in[16];
  const float* bl3 = (const float*)d_in[17];
  const float* Wr3 = (const float*)d_in[18];
  const float* Ws3 = (const float*)d_in[19];
  const float* bs3 = (const float*)d_in[20];
  const float* g3  = (const float*)d_in[21];
  const float* be3 = (const float*)d_in[22];
  const float* Wl4 = (const float*)d_in[23];
  const float* bl4 = (const float*)d_in[24];
  const float* Wr4 = (const float*)d_in[25];
  const float* Ws4 = (const float*)d_in[26];
  const float* bs4 = (const float*)d_in[27];

  // ---- workspace map (~133 MB) ----
  char* wsB = (char*)d_ws;
  float* Z    = (float*)wsB;                          // 50000*256*4 = 51.2 MB
  ushort* aggP = (ushort*)wsB;                        // aliases Z (dead before Z写)
  ushort* hAP = (ushort*)(wsB + 51200000);            // 32*2*NP*16 = 51.25 MB
  ushort* hCP = hAP;                                  // aliases hAP (dead after L2 gemm)
  ushort* xP  = (ushort*)(wsB + 51200000 + 51249152); // 16*2*NP*16 = 25.62 MB
  ushort* hBP = xP;                                   // aliases xP (dead after L1 gemm)
  char* p = wsB + 51200000 + 51249152 + 25624576;
  ushort* W1p = (ushort*)p; p += 262144;              // 32kb*2*256*16
  ushort* W2p = (ushort*)p; p += 262144;
  ushort* W3p = (ushort*)p; p += 65536;               // 16kb*2*128*16
  ushort* W4p = (ushort*)p; p += 32768;               // 8kb*2*128*16
  float* sums = (float*)p; p += 512 * 4;
  float* ab   = (float*)p; p += 512 * 4;
  float* bias2 = (float*)p; p += 256 * 4;
  float* invc = (float*)p; p += (size_t)N * 4;
  int* cnt    = (int*)p; p += (size_t)N * 4;
  int* offs   = (int*)p; p += (size_t)N * 4;
  int* cursor = (int*)p; p += (size_t)N * 4;
  int* btot   = (int*)p; p += 256;
  int* adj    = (int*)p;                              // E*4 = 3.2 MB

  hipMemsetAsync(cnt, 0, sizeof(int) * N, stream);
  int eb = (E + 255) / 256;
  int nb = (N + 1023) / 1024;  // 49
  count_deg<<<eb, 256, 0, stream>>>(dsts, cnt, E);
  scan_block<<<nb, 1024, 0, stream>>>(cnt, offs, btot, N);
  scan_tops<<<1, 64, 0, stream>>>(btot, nb);
  finalize_csr<<<(N + 255) / 256, 256, 0, stream>>>(offs, btot, cnt, cursor, invc, N);
  fill_adj<<<eb, 256, 0, stream>>>(srcs, dsts, cursor, adj, E);

  pack_x<<<NP * 16 / 256, 256, 0, stream>>>(x, xP, N);
  prep_w<1><<<32 * 256 / 256, 256, 0, stream>>>(Wl1, Wr1, Ws1, nullptr, W1p,
                                                256, 128, 256, 256, 256);

  const int RB = NP / 128;  // 391
  const float invN = 1.0f / (float)N;

  // L1: aggregate x (packed), then [aggP|xP] @ W1p -> hAP (bias+relu+stats)
  aggregate1<<<NP, 128, 0, stream>>>(x, adj, offs, cnt, invc, aggP, sums, N);
  gemm_pk<1, 1, 8, 128><<<dim3(RB, 2), 256, 0, stream>>>(
      aggP, xP, W1p, bl1, bs1, nullptr, hAP, sums, N, 256, 256);
  bn_affine<<<1, 256, 0, stream>>>(sums, g1, be1, ab, 256, invN);

  // L2: W2' = diag(a1)[Wl2|Wr2+Ws2]; Z = hA @ W2'; combine -> hBP
  prep_w<0><<<32 * 256 / 256, 256, 0, stream>>>(Wl2, Wr2, Ws2, ab, W2p,
                                                256, 0, 128, 256, 256);
  prep_bias<<<128, 256, 0, stream>>>(Wl2, Wr2, Ws2, bl2, bs2, ab, bias2, 256, 128);
  gemm_pk<0, 0, 8, 0><<<dim3(RB, 2), 256, 0, stream>>>(
      hAP, nullptr, W2p, nullptr, nullptr, Z, nullptr, nullptr, N, 256, 256);
  combine<128, 7, 128, 1, 1, 1><<<2048, 256, 0, stream>>>(
      Z, adj, offs, cnt, invc, bias2, nullptr, hBP, sums, N);
  bn_affine<<<1, 128, 0, stream>>>(sums, g2, be2, ab, 128, invN);

  // L3
  prep_w<0><<<16 * 128 / 256, 256, 0, stream>>>(Wl3, Wr3, Ws3, ab, W3p,
                                                128, 0, 64, 128, 128);
  prep_bias<<<64, 256, 0, stream>>>(Wl3, Wr3, Ws3, bl3, bs3, ab, bias2, 128, 64);
  gemm_pk<0, 0, 4, 0><<<dim3(RB, 1), 256, 0, stream>>>(
      hBP, nullptr, W3p, nullptr, nullptr, Z, nullptr, nullptr, N, 128, 128);
  combine<64, 6, 64, 1, 1, 1><<<2048, 256, 0, stream>>>(
      Z, adj, offs, cnt, invc, bias2, nullptr, hCP, sums, N);
  bn_affine<<<1, 64, 0, stream>>>(sums, g3, be3, ab, 64, invN);

  // L4: Mp=80, Mpad=128 (pad cols zeroed in prep_w)
  prep_w<0><<<8 * 128 / 256, 256, 0, stream>>>(Wl4, Wr4, Ws4, ab, W4p,
                                               64, 0, 40, 80, 128);
  prep_bias<<<40, 256, 0, stream>>>(Wl4, Wr4, Ws4, bl4, bs4, ab, bias2, 64, 40);
  gemm_pk<0, 0, 2, 0><<<dim3(RB, 1), 256, 0, stream>>>(
      hCP, nullptr, W4p, nullptr, nullptr, Z, nullptr, nullptr, N, 80, 128);
  combine<64, 6, 40, 0, 0, 0><<<2048, 256, 0, stream>>>(
      Z, adj, offs, cnt, invc, bias2, (float*)d_out, nullptr, nullptr, N);
}

// Round 8
// 629.536 us; speedup vs baseline: 1.3935x; 1.0507x over previous
//
#include <hip/hip_runtime.h>

// GNN: 4x GraphSAGE(mean) + skip Linear + BN(1-3) + ReLU(1-3), fp32.
// N=50000 nodes, E=800000 edges, dims 128->256->128->64->40.
//
// Round 8 = round 7 resubmit (r7 bench was a GPU-acquisition timeout).
// Gathers are the bottleneck (combine L2 = 115 us, fill-bound, FETCH ~=
// gather bytes). Store gathered operands in bf16:
//  - gemm_pk (L2-4) writes Zl (gathered half) bf16, Zr (root half) fp32.
//  - aggregate1 gathers from bf16 copy of x (pack_x emits it).
//  Halves gather traffic (-587 MB). Root paths stay fp32.
// Carried structure: BN folded into weights (prep_w) + bias2 (prep_bias);
// GEMM A-operands packed bf16 hi/lo fragment-planar; gemm_pk has no LDS/
// barriers (48 MFMA per K-32 step); combine does mean+root+bias(+relu+stats).

static constexpr int NN = 50000;
static constexpr int NE = 800000;
static constexpr int NP = 50048;   // rows padded to 128

typedef __attribute__((ext_vector_type(8))) short short8;
typedef __attribute__((ext_vector_type(4))) float f32x4;

__device__ __forceinline__ unsigned short bf16rne(float x) {
  unsigned u = __float_as_uint(x);
  return (unsigned short)((u + 0x7FFFu + ((u >> 16) & 1u)) >> 16);
}
__device__ __forceinline__ float bf2f(unsigned short h) {
  return __uint_as_float(((unsigned)h) << 16);
}

// ---------------- CSR build ----------------
__global__ void count_deg(const int* __restrict__ dst, int* __restrict__ cnt, int E) {
  int e = blockIdx.x * blockDim.x + threadIdx.x;
  if (e < E) atomicAdd(&cnt[dst[e]], 1);
}

__global__ __launch_bounds__(1024) void scan_block(const int* __restrict__ cnt,
                                                   int* __restrict__ excl,
                                                   int* __restrict__ btot, int n) {
  __shared__ int lds[1024];
  int i = blockIdx.x * 1024 + threadIdx.x;
  int v = (i < n) ? cnt[i] : 0;
  lds[threadIdx.x] = v;
  __syncthreads();
#pragma unroll
  for (int off = 1; off < 1024; off <<= 1) {
    int t = 0;
    if ((int)threadIdx.x >= off) t = lds[threadIdx.x - off];
    __syncthreads();
    lds[threadIdx.x] += t;
    __syncthreads();
  }
  if (i < n) excl[i] = lds[threadIdx.x] - v;
  if (threadIdx.x == 1023) btot[blockIdx.x] = lds[1023];
}

__global__ void scan_tops(int* __restrict__ btot, int nb) {
  int t = threadIdx.x;
  int v = (t < nb) ? btot[t] : 0;
  int own = v;
#pragma unroll
  for (int off = 1; off < 64; off <<= 1) {
    int u = __shfl_up(v, off);
    if (t >= off) v += u;
  }
  if (t < nb) btot[t] = v - own;
}

__global__ void finalize_csr(int* __restrict__ offs, const int* __restrict__ btot,
                             const int* __restrict__ cnt, int* __restrict__ cursor,
                             float* __restrict__ inv, int n) {
  int i = blockIdx.x * blockDim.x + threadIdx.x;
  if (i < n) {
    int o = offs[i] + btot[i >> 10];
    offs[i] = o;
    cursor[i] = o;
    int c = cnt[i];
    inv[i] = 1.0f / (float)(c > 0 ? c : 1);
  }
}

__global__ void fill_adj(const int* __restrict__ src, const int* __restrict__ dst,
                         int* __restrict__ cursor, int* __restrict__ adj, int E) {
  int e = blockIdx.x * blockDim.x + threadIdx.x;
  if (e < E) {
    int p = atomicAdd(&cursor[dst[e]], 1);
    adj[p] = src[e];
  }
}

// ---------------- packing ----------------
// x -> packed hi/lo planes (xP) + row-major bf16 copy (xb) for the gather.
__global__ void pack_x(const float* __restrict__ x, ushort* __restrict__ xP,
                       ushort* __restrict__ xb, int N) {
  int gid = blockIdx.x * 256 + threadIdx.x;
  int row = gid >> 4, kb = gid & 15;
  if (row >= NP) return;
  float v[8];
  if (row < N) {
    float4 a = *(const float4*)&x[(size_t)row * 128 + kb * 8];
    float4 b = *(const float4*)&x[(size_t)row * 128 + kb * 8 + 4];
    v[0]=a.x; v[1]=a.y; v[2]=a.z; v[3]=a.w; v[4]=b.x; v[5]=b.y; v[6]=b.z; v[7]=b.w;
  } else {
#pragma unroll
    for (int j = 0; j < 8; ++j) v[j] = 0.f;
  }
  short8 H, L;
#pragma unroll
  for (int j = 0; j < 8; ++j) {
    unsigned short h = bf16rne(v[j]);
    H[j] = (short)h;
    L[j] = (short)bf16rne(v[j] - bf2f(h));
  }
  *(short8*)&xP[((size_t)(kb * 2) * NP + row) * 8] = H;
  *(short8*)&xP[((size_t)(kb * 2 + 1) * NP + row) * 8] = L;
  *(short8*)&xb[(size_t)row * 128 + kb * 8] = H;
}

// Pack weights in B-fragment layout, with optional BN fold (w *= a[k]).
template <int L1V>
__global__ void prep_w(const float* __restrict__ Wl, const float* __restrict__ Wr,
                       const float* __restrict__ Wsk, const float* __restrict__ ab,
                       ushort* __restrict__ Wp, int K, int K1, int M, int Mp, int Mpad) {
  int gid = blockIdx.x * 256 + threadIdx.x;
  int col = gid % Mpad, kb = gid / Mpad;
  if (kb >= (K >> 3)) return;
  short8 H, L;
#pragma unroll
  for (int j = 0; j < 8; ++j) {
    int k = kb * 8 + j;
    float v = 0.f;
    if (col < Mp) {
      if (L1V) {
        v = (k < K1) ? Wl[(size_t)k * M + col]
                     : Wr[(size_t)(k - K1) * M + col] + Wsk[(size_t)(k - K1) * M + col];
      } else {
        float w = (col < M) ? Wl[(size_t)k * M + col]
                            : Wr[(size_t)k * M + (col - M)] + Wsk[(size_t)k * M + (col - M)];
        v = ab[k] * w;
      }
    }
    unsigned short h = bf16rne(v);
    H[j] = (short)h;
    L[j] = (short)bf16rne(v - bf2f(h));
  }
  *(short8*)&Wp[((size_t)(kb * 2) * Mpad + col) * 8] = H;
  *(short8*)&Wp[((size_t)(kb * 2 + 1) * Mpad + col) * 8] = L;
}

// bias_all[c] = bl+bs+sum_k b[k](Wr+Ws)[k][c]; bias_deg[c] = sum_k b[k]Wl[k][c]
__global__ void prep_bias(const float* __restrict__ Wl, const float* __restrict__ Wr,
                          const float* __restrict__ Wsk, const float* __restrict__ bl,
                          const float* __restrict__ bs, const float* __restrict__ ab,
                          float* __restrict__ bias2, int K, int M) {
  int c = blockIdx.x;
  int k = threadIdx.x;
  float va = 0.f, vd = 0.f;
  if (k < K) {
    float b = ab[K + k];
    vd = b * Wl[(size_t)k * M + c];
    va = b * (Wr[(size_t)k * M + c] + Wsk[(size_t)k * M + c]);
  }
  __shared__ float r[512];
  r[k] = va;
  r[256 + k] = vd;
  __syncthreads();
  for (int off = 128; off > 0; off >>= 1) {
    if (k < off) {
      r[k] += r[k + off];
      r[256 + k] += r[256 + k + off];
    }
    __syncthreads();
  }
  if (k == 0) {
    bias2[c] = bl[c] + bs[c] + r[0];
    bias2[M + c] = r[256];
  }
}

// ---------------- aggregation (L1) ----------------
// mean of bf16(x) over incoming nbrs, written PACKED. grid = NP.
__global__ void aggregate1(const ushort* __restrict__ xb, const int* __restrict__ adj,
                           const int* __restrict__ offs, const int* __restrict__ cnt,
                           const float* __restrict__ inv, ushort* __restrict__ aggP,
                           float* __restrict__ sums, int N) {
  const int D = 128;
  int n = blockIdx.x;
  int t = threadIdx.x;
  if (n == 0) {
    for (int j = t; j < 512; j += D) sums[j] = 0.f;
  }
  float m = 0.f;
  if (n < N) {
    int off = offs[n];
    int deg = cnt[n];
    const ushort* __restrict__ hp = xb + t;
    float s = 0.f;
    int i = 0;
    for (; i + 4 <= deg; i += 4) {
      int s0 = adj[off + i + 0];
      int s1 = adj[off + i + 1];
      int s2 = adj[off + i + 2];
      int s3 = adj[off + i + 3];
      float v0 = bf2f(hp[(size_t)s0 * D]);
      float v1 = bf2f(hp[(size_t)s1 * D]);
      float v2 = bf2f(hp[(size_t)s2 * D]);
      float v3 = bf2f(hp[(size_t)s3 * D]);
      s += (v0 + v1) + (v2 + v3);
    }
    for (; i < deg; ++i) s += bf2f(hp[(size_t)adj[off + i] * D]);
    m = s * inv[n];
  }
  unsigned short hh = bf16rne(m);
  unsigned short ll = bf16rne(m - bf2f(hh));
  size_t base = ((size_t)((t >> 3) * 2) * NP + n) * 8 + (t & 7);
  aggP[base] = hh;
  aggP[base + (size_t)NP * 8] = ll;
}

// ---------------- MFMA GEMM (no LDS, no barriers) ----------------
// C[N x Mp] = A @ B, A packed (TWO_A: [A1|A2] along K at KT1), B packed.
// EPI=1 (L1): +bias(bl+bs), relu, BN stats, PACKED output (OutP).
// EPI=0: Zl (cols<M) bf16 -> OutL; Zr (cols M..Mp) fp32 -> OutR. Stride M.
template <int TWO_A, int EPI, int NK32, int KT1>
__global__ __launch_bounds__(256) void gemm_pk(
    const ushort* __restrict__ A1, const ushort* __restrict__ A2,
    const ushort* __restrict__ B, const float* __restrict__ bl,
    const float* __restrict__ bs, ushort* __restrict__ OutL,
    float* __restrict__ OutR, ushort* __restrict__ OutP,
    float* __restrict__ sums, int N, int M, int Mp, int Mpad) {
  const int tid = threadIdx.x;
  const int l = tid & 63;
  const int w = tid >> 6;
  const int wr = w >> 1, wc = w & 1;
  const int l16 = l & 15, lh = l >> 4;
  const int row0 = blockIdx.x * 128, col0 = blockIdx.y * 128;

  const f32x4 z4 = {0.f, 0.f, 0.f, 0.f};
  f32x4 acc[4][4];
#pragma unroll
  for (int m = 0; m < 4; ++m)
#pragma unroll
    for (int n = 0; n < 4; ++n) acc[m][n] = z4;

  const int arow = row0 + wr * 64 + l16;
  const int bcol = col0 + wc * 64 + l16;

#pragma unroll 2
  for (int it = 0; it < NK32; ++it) {
    const int kbase = it * 32;
    const ushort* Ap = A1;
    int kloc = kbase;
    if (TWO_A && kbase >= KT1) { Ap = A2; kloc = kbase - KT1; }
    const int akb = (kloc >> 3) + lh;
    const int bkb = (kbase >> 3) + lh;
    const ushort* a_hi = Ap + ((size_t)(akb * 2) * NP + arow) * 8;
    const ushort* a_lo = a_hi + (size_t)NP * 8;
    const ushort* b_hi = B + ((size_t)(bkb * 2) * Mpad + bcol) * 8;
    const ushort* b_lo = b_hi + (size_t)Mpad * 8;

    short8 ah[4], al[4], bh[4], blo[4];
#pragma unroll
    for (int m = 0; m < 4; ++m) {
      ah[m] = *(const short8*)(a_hi + m * 128);
      al[m] = *(const short8*)(a_lo + m * 128);
    }
#pragma unroll
    for (int n = 0; n < 4; ++n) {
      bh[n] = *(const short8*)(b_hi + n * 128);
      blo[n] = *(const short8*)(b_lo + n * 128);
    }
#pragma unroll
    for (int m = 0; m < 4; ++m)
#pragma unroll
      for (int n = 0; n < 4; ++n) {
        acc[m][n] = __builtin_amdgcn_mfma_f32_16x16x32_bf16(ah[m], bh[n], acc[m][n], 0, 0, 0);
        acc[m][n] = __builtin_amdgcn_mfma_f32_16x16x32_bf16(ah[m], blo[n], acc[m][n], 0, 0, 0);
        acc[m][n] = __builtin_amdgcn_mfma_f32_16x16x32_bf16(al[m], bh[n], acc[m][n], 0, 0, 0);
      }
  }

  const int lr = lh * 4;
  if (EPI) {
    __shared__ float st[2048];
    float cs[4] = {0.f, 0.f, 0.f, 0.f}, cq[4] = {0.f, 0.f, 0.f, 0.f};
#pragma unroll
    for (int n = 0; n < 4; ++n) {
      int col = col0 + wc * 64 + n * 16 + l16;
      bool cok = col < Mp;
      float bias = cok ? (bl[col] + bs[col]) : 0.f;
      int cb = col >> 3, ch = col & 7;
      size_t hbase = ((size_t)(cb * 2) * NP) * 8 + ch;
      size_t lbase = hbase + (size_t)NP * 8;
#pragma unroll
      for (int m = 0; m < 4; ++m)
#pragma unroll
        for (int i = 0; i < 4; ++i) {
          int row = row0 + wr * 64 + m * 16 + lr + i;
          float v = acc[m][n][i] + bias;
          v = fmaxf(v, 0.f);
          if (cok && row < N) {
            unsigned short hh = bf16rne(v);
            OutP[hbase + (size_t)row * 8] = hh;
            OutP[lbase + (size_t)row * 8] = bf16rne(v - bf2f(hh));
            cs[n] += v;
            cq[n] += v * v;
          }
        }
    }
    int slot = wr * 4 + lh;
#pragma unroll
    for (int n = 0; n < 4; ++n) {
      int c = wc * 64 + n * 16 + l16;
      st[c * 8 + slot] = cs[n];
      st[1024 + c * 8 + slot] = cq[n];
    }
    __syncthreads();
    if (tid < 128) {
      float s1 = 0.f, s2 = 0.f;
#pragma unroll
      for (int t2 = 0; t2 < 8; ++t2) {
        s1 += st[tid * 8 + t2];
        s2 += st[1024 + tid * 8 + t2];
      }
      int c = col0 + tid;
      if (c < Mp) {
        atomicAdd(&sums[c], s1);
        atomicAdd(&sums[Mp + c], s2);
      }
    }
  } else {
#pragma unroll
    for (int n = 0; n < 4; ++n) {
      int col = col0 + wc * 64 + n * 16 + l16;
      if (col >= Mp) continue;
      bool isL = col < M;
      int colR = col - M;
#pragma unroll
      for (int m = 0; m < 4; ++m)
#pragma unroll
        for (int i = 0; i < 4; ++i) {
          int row = row0 + wr * 64 + m * 16 + lr + i;
          if (row < N) {
            float v = acc[m][n][i];
            if (isL) OutL[(size_t)row * M + col] = bf16rne(v);
            else     OutR[(size_t)row * M + colR] = v;
          }
        }
    }
  }
}

// ---------------- combine (L2-4) ----------------
// y = mean_nbrs(bf16 Zl[src]) + Zr + bias_all + (deg>0 ? bias_deg : 0).
// PACK=1: write packed hi/lo fragment-planar; else fp32 out (row stride M).
template <int DPAD, int LOGD, int M, int RELU, int STATS, int PACK>
__global__ __launch_bounds__(256) void combine(
    const ushort* __restrict__ Zl, const float* __restrict__ Zr,
    const int* __restrict__ adj, const int* __restrict__ offs,
    const int* __restrict__ cnt, const float* __restrict__ inv,
    const float* __restrict__ bias2, float* __restrict__ outF,
    ushort* __restrict__ outP, float* __restrict__ sums, int N) {
  constexpr int S = 256 / DPAD;
  const int tid = threadIdx.x;
  const int c = tid & (DPAD - 1);
  const int sub = tid >> LOGD;
  const bool act = (c < M);
  const float b_all = act ? bias2[c] : 0.f;
  const float b_deg = act ? bias2[M + c] : 0.f;
  float cs = 0.f, cq = 0.f;
  const ushort* __restrict__ Zc = Zl + c;
  for (int n = blockIdx.x * S + sub; n < N; n += gridDim.x * S) {
    if (act) {
      int off = offs[n], deg = cnt[n];
      float s = 0.f;
      int i = 0;
      for (; i + 4 <= deg; i += 4) {
        int s0 = adj[off + i + 0];
        int s1 = adj[off + i + 1];
        int s2 = adj[off + i + 2];
        int s3 = adj[off + i + 3];
        float v0 = bf2f(Zc[(size_t)s0 * M]);
        float v1 = bf2f(Zc[(size_t)s1 * M]);
        float v2 = bf2f(Zc[(size_t)s2 * M]);
        float v3 = bf2f(Zc[(size_t)s3 * M]);
        s += (v0 + v1) + (v2 + v3);
      }
      for (; i < deg; ++i) s += bf2f(Zc[(size_t)adj[off + i] * M]);
      float y = fmaf(s, inv[n], Zr[(size_t)n * M + c] + b_all);
      if (deg > 0) y += b_deg;
      if (RELU) y = fmaxf(y, 0.f);
      if (PACK) {
        unsigned short hh = bf16rne(y);
        size_t base = ((size_t)((c >> 3) * 2) * NP + n) * 8 + (c & 7);
        outP[base] = hh;
        outP[base + (size_t)NP * 8] = bf16rne(y - bf2f(hh));
      } else {
        outF[(size_t)n * M + c] = y;
      }
      if (STATS) { cs += y; cq += y * y; }
    }
  }
  if (STATS) {
    __shared__ float red[512];
    red[tid] = cs;
    red[256 + tid] = cq;
    __syncthreads();
    if (sub == 0 && act) {
#pragma unroll
      for (int s2 = 1; s2 < S; ++s2) {
        cs += red[s2 * DPAD + c];
        cq += red[256 + s2 * DPAD + c];
      }
      atomicAdd(&sums[c], cs);
      atomicAdd(&sums[M + c], cq);
    }
  }
}

__global__ void bn_affine(float* __restrict__ sums, const float* __restrict__ g,
                          const float* __restrict__ be, float* __restrict__ ab,
                          int M, float invN) {
  int j = threadIdx.x;
  if (j < M) {
    float s1 = sums[j], s2 = sums[M + j];
    float mu = s1 * invN;
    float var = fmaf(-mu, mu, s2 * invN);
    float a = g[j] / sqrtf(var + 1e-5f);
    ab[j] = a;
    ab[M + j] = fmaf(-mu, a, be[j]);
    sums[j] = 0.f;
    sums[M + j] = 0.f;
  }
}

extern "C" void kernel_launch(void* const* d_in, const int* in_sizes, int n_in,
                              void* d_out, int out_size, void* d_ws, size_t ws_size,
                              hipStream_t stream) {
  const int N = NN, E = NE;
  const float* x = (const float*)d_in[0];
  const int* ei = (const int*)d_in[1];
  const int* srcs = ei;
  const int* dsts = ei + E;

  const float* Wl1 = (const float*)d_in[2];
  const float* bl1 = (const float*)d_in[3];
  const float* Wr1 = (const float*)d_in[4];
  const float* Ws1 = (const float*)d_in[5];
  const float* bs1 = (const float*)d_in[6];
  const float* g1  = (const float*)d_in[7];
  const float* be1 = (const float*)d_in[8];
  const float* Wl2 = (const float*)d_in[9];
  const float* bl2 = (const float*)d_in[10];
  const float* Wr2 = (const float*)d_in[11];
  const float* Ws2 = (const float*)d_in[12];
  const float* bs2 = (const float*)d_in[13];
  const float* g2  = (const float*)d_in[14];
  const float* be2 = (const float*)d_in[15];
  const float* Wl3 = (const float*)d_in[16];
  const float* bl3 = (const float*)d_in[17];
  const float* Wr3 = (const float*)d_in[18];
  const float* Ws3 = (const float*)d_in[19];
  const float* bs3 = (const float*)d_in[20];
  const float* g3  = (const float*)d_in[21];
  const float* be3 = (const float*)d_in[22];
  const float* Wl4 = (const float*)d_in[23];
  const float* bl4 = (const float*)d_in[24];
  const float* Wr4 = (const float*)d_in[25];
  const float* Ws4 = (const float*)d_in[26];
  const float* bs4 = (const float*)d_in[27];

  // ---- workspace map (~116 MB) ----
  // A: hAP (K=256 packed, 51.25MB); hCP (K=64, 12.8MB) aliases.
  // B: xP (K=128 packed, 25.62MB); hBP aliases.
  // C: aggP (25.62MB); Zr fp32 (max N*128*4=25.6MB) aliases.
  // D: xb bf16 NP*128 (12.81MB); Zl bf16 (max N*128*2=12.8MB) aliases.
  char* wsB = (char*)d_ws;
  ushort* hAP = (ushort*)wsB;
  ushort* hCP = hAP;
  ushort* xP  = (ushort*)(wsB + 51249152);
  ushort* hBP = xP;
  char* regC  = wsB + 51249152 + 25624576;
  ushort* aggP = (ushort*)regC;
  float* Zr   = (float*)regC;
  char* regD  = regC + 25624576;
  ushort* xb  = (ushort*)regD;
  ushort* Zl  = (ushort*)regD;
  char* p = regD + (size_t)NP * 128 * 2;
  ushort* W1p = (ushort*)p; p += 262144;
  ushort* W2p = (ushort*)p; p += 262144;
  ushort* W3p = (ushort*)p; p += 65536;
  ushort* W4p = (ushort*)p; p += 32768;
  float* sums = (float*)p; p += 512 * 4;
  float* ab   = (float*)p; p += 512 * 4;
  float* bias2 = (float*)p; p += 256 * 4;
  float* invc = (float*)p; p += (size_t)N * 4;
  int* cnt    = (int*)p; p += (size_t)N * 4;
  int* offs   = (int*)p; p += (size_t)N * 4;
  int* cursor = (int*)p; p += (size_t)N * 4;
  int* btot   = (int*)p; p += 256;
  int* adj    = (int*)p;

  hipMemsetAsync(cnt, 0, sizeof(int) * N, stream);
  int eb = (E + 255) / 256;
  int nb = (N + 1023) / 1024;  // 49
  count_deg<<<eb, 256, 0, stream>>>(dsts, cnt, E);
  scan_block<<<nb, 1024, 0, stream>>>(cnt, offs, btot, N);
  scan_tops<<<1, 64, 0, stream>>>(btot, nb);
  finalize_csr<<<(N + 255) / 256, 256, 0, stream>>>(offs, btot, cnt, cursor, invc, N);
  fill_adj<<<eb, 256, 0, stream>>>(srcs, dsts, cursor, adj, E);

  pack_x<<<NP * 16 / 256, 256, 0, stream>>>(x, xP, xb, N);
  prep_w<1><<<32 * 256 / 256, 256, 0, stream>>>(Wl1, Wr1, Ws1, nullptr, W1p,
                                                256, 128, 256, 256, 256);

  const int RB = NP / 128;  // 391
  const float invN = 1.0f / (float)N;

  // L1: aggregate bf16(x) (packed out), then [aggP|xP] @ W1p -> hAP
  aggregate1<<<NP, 128, 0, stream>>>(xb, adj, offs, cnt, invc, aggP, sums, N);
  gemm_pk<1, 1, 8, 128><<<dim3(RB, 2), 256, 0, stream>>>(
      aggP, xP, W1p, bl1, bs1, nullptr, nullptr, hAP, sums, N, 256, 256, 256);
  bn_affine<<<1, 256, 0, stream>>>(sums, g1, be1, ab, 256, invN);

  // L2: Z = hA @ diag(a1)[Wl2|Wr2+Ws2] -> Zl bf16 + Zr fp32; combine -> hBP
  prep_w<0><<<32 * 256 / 256, 256, 0, stream>>>(Wl2, Wr2, Ws2, ab, W2p,
                                                256, 0, 128, 256, 256);
  prep_bias<<<128, 256, 0, stream>>>(Wl2, Wr2, Ws2, bl2, bs2, ab, bias2, 256, 128);
  gemm_pk<0, 0, 8, 0><<<dim3(RB, 2), 256, 0, stream>>>(
      hAP, nullptr, W2p, nullptr, nullptr, Zl, Zr, nullptr, nullptr, N, 128, 256, 256);
  combine<128, 7, 128, 1, 1, 1><<<2048, 256, 0, stream>>>(
      Zl, Zr, adj, offs, cnt, invc, bias2, nullptr, hBP, sums, N);
  bn_affine<<<1, 128, 0, stream>>>(sums, g2, be2, ab, 128, invN);

  // L3
  prep_w<0><<<16 * 128 / 256, 256, 0, stream>>>(Wl3, Wr3, Ws3, ab, W3p,
                                                128, 0, 64, 128, 128);
  prep_bias<<<64, 256, 0, stream>>>(Wl3, Wr3, Ws3, bl3, bs3, ab, bias2, 128, 64);
  gemm_pk<0, 0, 4, 0><<<dim3(RB, 1), 256, 0, stream>>>(
      hBP, nullptr, W3p, nullptr, nullptr, Zl, Zr, nullptr, nullptr, N, 64, 128, 128);
  combine<64, 6, 64, 1, 1, 1><<<2048, 256, 0, stream>>>(
      Zl, Zr, adj, offs, cnt, invc, bias2, nullptr, hCP, sums, N);
  bn_affine<<<1, 64, 0, stream>>>(sums, g3, be3, ab, 64, invN);

  // L4: Mp=80 (Mpad=128, pad cols zeroed in prep_w)
  prep_w<0><<<8 * 128 / 256, 256, 0, stream>>>(Wl4, Wr4, Ws4, ab, W4p,
                                               64, 0, 40, 80, 128);
  prep_bias<<<40, 256, 0, stream>>>(Wl4, Wr4, Ws4, bl4, bs4, ab, bias2, 64, 40);
  gemm_pk<0, 0, 2, 0><<<dim3(RB, 1), 256, 0, stream>>>(
      hCP, nullptr, W4p, nullptr, nullptr, Zl, Zr, nullptr, nullptr, N, 40, 80, 128);
  combine<64, 6, 40, 0, 0, 0><<<2048, 256, 0, stream>>>(
      Zl, Zr, adj, offs, cnt, invc, bias2, (float*)d_out, nullptr, nullptr, N);
}

// Round 11
// 570.681 us; speedup vs baseline: 1.5372x; 1.1031x over previous
//
#include <hip/hip_runtime.h>

// GNN: 4x GraphSAGE(mean) + skip Linear + BN(1-3) + ReLU(1-3), fp32.
// N=50000 nodes, E=800000 edges, dims 128->256->128->64->40.
//
// Round 11 = round 9 resubmit (r9, r10 benches were GPU-acquisition
// timeouts; the wide-gather experiment has never run).
// combine/aggregate gathers are load-ISSUE bound, not BW bound
// (r8: FETCH halved 199->103MB but time only 115->104us; 2B/lane gathers).
// Widen gathers to 8B/lane (ushort4 = 4 columns per lane):
//  - combine: G=M/4 lanes per node, one ushort4 per neighbor per lane.
//  - aggregate1: 32 lanes/node, ushort4 gathers + packed ushort4 writes.
//  4x fewer gather instructions, 4x more bytes in flight per wave.
// Carried: BN folded into weights (prep_w/prep_bias); A-operands packed
// bf16 hi/lo fragment-planar; gemm_pk no-LDS no-barrier (48 MFMA / K-32);
// Zl bf16 + Zr fp32 split outputs.

static constexpr int NN = 50000;
static constexpr int NE = 800000;
static constexpr int NP = 50048;   // rows padded to 128

typedef __attribute__((ext_vector_type(8))) short short8;
typedef __attribute__((ext_vector_type(4))) float f32x4;

__device__ __forceinline__ unsigned short bf16rne(float x) {
  unsigned u = __float_as_uint(x);
  return (unsigned short)((u + 0x7FFFu + ((u >> 16) & 1u)) >> 16);
}
__device__ __forceinline__ float bf2f(unsigned short h) {
  return __uint_as_float(((unsigned)h) << 16);
}

// ---------------- CSR build ----------------
__global__ void count_deg(const int* __restrict__ dst, int* __restrict__ cnt, int E) {
  int e = blockIdx.x * blockDim.x + threadIdx.x;
  if (e < E) atomicAdd(&cnt[dst[e]], 1);
}

__global__ __launch_bounds__(1024) void scan_block(const int* __restrict__ cnt,
                                                   int* __restrict__ excl,
                                                   int* __restrict__ btot, int n) {
  __shared__ int lds[1024];
  int i = blockIdx.x * 1024 + threadIdx.x;
  int v = (i < n) ? cnt[i] : 0;
  lds[threadIdx.x] = v;
  __syncthreads();
#pragma unroll
  for (int off = 1; off < 1024; off <<= 1) {
    int t = 0;
    if ((int)threadIdx.x >= off) t = lds[threadIdx.x - off];
    __syncthreads();
    lds[threadIdx.x] += t;
    __syncthreads();
  }
  if (i < n) excl[i] = lds[threadIdx.x] - v;
  if (threadIdx.x == 1023) btot[blockIdx.x] = lds[1023];
}

__global__ void scan_tops(int* __restrict__ btot, int nb) {
  int t = threadIdx.x;
  int v = (t < nb) ? btot[t] : 0;
  int own = v;
#pragma unroll
  for (int off = 1; off < 64; off <<= 1) {
    int u = __shfl_up(v, off);
    if (t >= off) v += u;
  }
  if (t < nb) btot[t] = v - own;
}

__global__ void finalize_csr(int* __restrict__ offs, const int* __restrict__ btot,
                             const int* __restrict__ cnt, int* __restrict__ cursor,
                             float* __restrict__ inv, int n) {
  int i = blockIdx.x * blockDim.x + threadIdx.x;
  if (i < n) {
    int o = offs[i] + btot[i >> 10];
    offs[i] = o;
    cursor[i] = o;
    int c = cnt[i];
    inv[i] = 1.0f / (float)(c > 0 ? c : 1);
  }
}

__global__ void fill_adj(const int* __restrict__ src, const int* __restrict__ dst,
                         int* __restrict__ cursor, int* __restrict__ adj, int E) {
  int e = blockIdx.x * blockDim.x + threadIdx.x;
  if (e < E) {
    int p = atomicAdd(&cursor[dst[e]], 1);
    adj[p] = src[e];
  }
}

// ---------------- packing ----------------
// x -> packed hi/lo planes (xP) + row-major bf16 copy (xb) for the gather.
__global__ void pack_x(const float* __restrict__ x, ushort* __restrict__ xP,
                       ushort* __restrict__ xb, int N) {
  int gid = blockIdx.x * 256 + threadIdx.x;
  int row = gid >> 4, kb = gid & 15;
  if (row >= NP) return;
  float v[8];
  if (row < N) {
    float4 a = *(const float4*)&x[(size_t)row * 128 + kb * 8];
    float4 b = *(const float4*)&x[(size_t)row * 128 + kb * 8 + 4];
    v[0]=a.x; v[1]=a.y; v[2]=a.z; v[3]=a.w; v[4]=b.x; v[5]=b.y; v[6]=b.z; v[7]=b.w;
  } else {
#pragma unroll
    for (int j = 0; j < 8; ++j) v[j] = 0.f;
  }
  short8 H, L;
#pragma unroll
  for (int j = 0; j < 8; ++j) {
    unsigned short h = bf16rne(v[j]);
    H[j] = (short)h;
    L[j] = (short)bf16rne(v[j] - bf2f(h));
  }
  *(short8*)&xP[((size_t)(kb * 2) * NP + row) * 8] = H;
  *(short8*)&xP[((size_t)(kb * 2 + 1) * NP + row) * 8] = L;
  *(short8*)&xb[(size_t)row * 128 + kb * 8] = H;
}

// Pack weights in B-fragment layout, with optional BN fold (w *= a[k]).
template <int L1V>
__global__ void prep_w(const float* __restrict__ Wl, const float* __restrict__ Wr,
                       const float* __restrict__ Wsk, const float* __restrict__ ab,
                       ushort* __restrict__ Wp, int K, int K1, int M, int Mp, int Mpad) {
  int gid = blockIdx.x * 256 + threadIdx.x;
  int col = gid % Mpad, kb = gid / Mpad;
  if (kb >= (K >> 3)) return;
  short8 H, L;
#pragma unroll
  for (int j = 0; j < 8; ++j) {
    int k = kb * 8 + j;
    float v = 0.f;
    if (col < Mp) {
      if (L1V) {
        v = (k < K1) ? Wl[(size_t)k * M + col]
                     : Wr[(size_t)(k - K1) * M + col] + Wsk[(size_t)(k - K1) * M + col];
      } else {
        float w = (col < M) ? Wl[(size_t)k * M + col]
                            : Wr[(size_t)k * M + (col - M)] + Wsk[(size_t)k * M + (col - M)];
        v = ab[k] * w;
      }
    }
    unsigned short h = bf16rne(v);
    H[j] = (short)h;
    L[j] = (short)bf16rne(v - bf2f(h));
  }
  *(short8*)&Wp[((size_t)(kb * 2) * Mpad + col) * 8] = H;
  *(short8*)&Wp[((size_t)(kb * 2 + 1) * Mpad + col) * 8] = L;
}

// bias_all[c] = bl+bs+sum_k b[k](Wr+Ws)[k][c]; bias_deg[c] = sum_k b[k]Wl[k][c]
__global__ void prep_bias(const float* __restrict__ Wl, const float* __restrict__ Wr,
                          const float* __restrict__ Wsk, const float* __restrict__ bl,
                          const float* __restrict__ bs, const float* __restrict__ ab,
                          float* __restrict__ bias2, int K, int M) {
  int c = blockIdx.x;
  int k = threadIdx.x;
  float va = 0.f, vd = 0.f;
  if (k < K) {
    float b = ab[K + k];
    vd = b * Wl[(size_t)k * M + c];
    va = b * (Wr[(size_t)k * M + c] + Wsk[(size_t)k * M + c]);
  }
  __shared__ float r[512];
  r[k] = va;
  r[256 + k] = vd;
  __syncthreads();
  for (int off = 128; off > 0; off >>= 1) {
    if (k < off) {
      r[k] += r[k + off];
      r[256 + k] += r[256 + k + off];
    }
    __syncthreads();
  }
  if (k == 0) {
    bias2[c] = bl[c] + bs[c] + r[0];
    bias2[M + c] = r[256];
  }
}

// ---------------- aggregation (L1) ----------------
// mean of bf16(x) over nbrs; 32 lanes/node, ushort4 (4-col) gathers.
// grid = NP/8 blocks x 256 thr (8 nodes/block). Block 0 zeroes sums.
__global__ __launch_bounds__(256) void aggregate1(
    const ushort* __restrict__ xb, const int* __restrict__ adj,
    const int* __restrict__ offs, const int* __restrict__ cnt,
    const float* __restrict__ inv, ushort* __restrict__ aggP,
    float* __restrict__ sums, int N) {
  const int tid = threadIdx.x;
  if (blockIdx.x == 0) {
    for (int j = tid; j < 512; j += 256) sums[j] = 0.f;
  }
  const int n = blockIdx.x * 8 + (tid >> 5);
  const int c4 = (tid & 31) * 4;
  float s0 = 0.f, s1 = 0.f, s2 = 0.f, s3 = 0.f;
  float invn = 0.f;
  if (n < N) {
    invn = inv[n];
    int off = offs[n], deg = cnt[n];
    const ushort* __restrict__ hp = xb + c4;
    int i = 0;
    for (; i + 4 <= deg; i += 4) {
      int a0 = adj[off + i + 0];
      int a1 = adj[off + i + 1];
      int a2 = adj[off + i + 2];
      int a3 = adj[off + i + 3];
      ushort4 v0 = *(const ushort4*)&hp[(size_t)a0 * 128];
      ushort4 v1 = *(const ushort4*)&hp[(size_t)a1 * 128];
      ushort4 v2 = *(const ushort4*)&hp[(size_t)a2 * 128];
      ushort4 v3 = *(const ushort4*)&hp[(size_t)a3 * 128];
      s0 += (bf2f(v0.x) + bf2f(v1.x)) + (bf2f(v2.x) + bf2f(v3.x));
      s1 += (bf2f(v0.y) + bf2f(v1.y)) + (bf2f(v2.y) + bf2f(v3.y));
      s2 += (bf2f(v0.z) + bf2f(v1.z)) + (bf2f(v2.z) + bf2f(v3.z));
      s3 += (bf2f(v0.w) + bf2f(v1.w)) + (bf2f(v2.w) + bf2f(v3.w));
    }
    for (; i < deg; ++i) {
      ushort4 v = *(const ushort4*)&hp[(size_t)adj[off + i] * 128];
      s0 += bf2f(v.x); s1 += bf2f(v.y); s2 += bf2f(v.z); s3 += bf2f(v.w);
    }
  }
  float m0 = s0 * invn, m1 = s1 * invn, m2 = s2 * invn, m3 = s3 * invn;
  ushort4 H, L;
  H.x = bf16rne(m0); L.x = bf16rne(m0 - bf2f(H.x));
  H.y = bf16rne(m1); L.y = bf16rne(m1 - bf2f(H.y));
  H.z = bf16rne(m2); L.z = bf16rne(m2 - bf2f(H.z));
  H.w = bf16rne(m3); L.w = bf16rne(m3 - bf2f(H.w));
  const int kb = c4 >> 3, sl = c4 & 7;
  size_t chunk = ((size_t)(kb * 2) * NP + n) * 8 + sl;
  *(ushort4*)&aggP[chunk] = H;
  *(ushort4*)&aggP[chunk + (size_t)NP * 8] = L;
}

// ---------------- MFMA GEMM (no LDS, no barriers) ----------------
// C[N x Mp] = A @ B, A packed (TWO_A: [A1|A2] along K at KT1), B packed.
// EPI=1 (L1): +bias(bl+bs), relu, BN stats, PACKED output (OutP).
// EPI=0: Zl (cols<M) bf16 -> OutL; Zr (cols M..Mp) fp32 -> OutR. Stride M.
template <int TWO_A, int EPI, int NK32, int KT1>
__global__ __launch_bounds__(256) void gemm_pk(
    const ushort* __restrict__ A1, const ushort* __restrict__ A2,
    const ushort* __restrict__ B, const float* __restrict__ bl,
    const float* __restrict__ bs, ushort* __restrict__ OutL,
    float* __restrict__ OutR, ushort* __restrict__ OutP,
    float* __restrict__ sums, int N, int M, int Mp, int Mpad) {
  const int tid = threadIdx.x;
  const int l = tid & 63;
  const int w = tid >> 6;
  const int wr = w >> 1, wc = w & 1;
  const int l16 = l & 15, lh = l >> 4;
  const int row0 = blockIdx.x * 128, col0 = blockIdx.y * 128;

  const f32x4 z4 = {0.f, 0.f, 0.f, 0.f};
  f32x4 acc[4][4];
#pragma unroll
  for (int m = 0; m < 4; ++m)
#pragma unroll
    for (int n = 0; n < 4; ++n) acc[m][n] = z4;

  const int arow = row0 + wr * 64 + l16;
  const int bcol = col0 + wc * 64 + l16;

#pragma unroll 2
  for (int it = 0; it < NK32; ++it) {
    const int kbase = it * 32;
    const ushort* Ap = A1;
    int kloc = kbase;
    if (TWO_A && kbase >= KT1) { Ap = A2; kloc = kbase - KT1; }
    const int akb = (kloc >> 3) + lh;
    const int bkb = (kbase >> 3) + lh;
    const ushort* a_hi = Ap + ((size_t)(akb * 2) * NP + arow) * 8;
    const ushort* a_lo = a_hi + (size_t)NP * 8;
    const ushort* b_hi = B + ((size_t)(bkb * 2) * Mpad + bcol) * 8;
    const ushort* b_lo = b_hi + (size_t)Mpad * 8;

    short8 ah[4], al[4], bh[4], blo[4];
#pragma unroll
    for (int m = 0; m < 4; ++m) {
      ah[m] = *(const short8*)(a_hi + m * 128);
      al[m] = *(const short8*)(a_lo + m * 128);
    }
#pragma unroll
    for (int n = 0; n < 4; ++n) {
      bh[n] = *(const short8*)(b_hi + n * 128);
      blo[n] = *(const short8*)(b_lo + n * 128);
    }
#pragma unroll
    for (int m = 0; m < 4; ++m)
#pragma unroll
      for (int n = 0; n < 4; ++n) {
        acc[m][n] = __builtin_amdgcn_mfma_f32_16x16x32_bf16(ah[m], bh[n], acc[m][n], 0, 0, 0);
        acc[m][n] = __builtin_amdgcn_mfma_f32_16x16x32_bf16(ah[m], blo[n], acc[m][n], 0, 0, 0);
        acc[m][n] = __builtin_amdgcn_mfma_f32_16x16x32_bf16(al[m], bh[n], acc[m][n], 0, 0, 0);
      }
  }

  const int lr = lh * 4;
  if (EPI) {
    __shared__ float st[2048];
    float cs[4] = {0.f, 0.f, 0.f, 0.f}, cq[4] = {0.f, 0.f, 0.f, 0.f};
#pragma unroll
    for (int n = 0; n < 4; ++n) {
      int col = col0 + wc * 64 + n * 16 + l16;
      bool cok = col < Mp;
      float bias = cok ? (bl[col] + bs[col]) : 0.f;
      int cb = col >> 3, ch = col & 7;
      size_t hbase = ((size_t)(cb * 2) * NP) * 8 + ch;
      size_t lbase = hbase + (size_t)NP * 8;
#pragma unroll
      for (int m = 0; m < 4; ++m)
#pragma unroll
        for (int i = 0; i < 4; ++i) {
          int row = row0 + wr * 64 + m * 16 + lr + i;
          float v = acc[m][n][i] + bias;
          v = fmaxf(v, 0.f);
          if (cok && row < N) {
            unsigned short hh = bf16rne(v);
            OutP[hbase + (size_t)row * 8] = hh;
            OutP[lbase + (size_t)row * 8] = bf16rne(v - bf2f(hh));
            cs[n] += v;
            cq[n] += v * v;
          }
        }
    }
    int slot = wr * 4 + lh;
#pragma unroll
    for (int n = 0; n < 4; ++n) {
      int c = wc * 64 + n * 16 + l16;
      st[c * 8 + slot] = cs[n];
      st[1024 + c * 8 + slot] = cq[n];
    }
    __syncthreads();
    if (tid < 128) {
      float s1 = 0.f, s2 = 0.f;
#pragma unroll
      for (int t2 = 0; t2 < 8; ++t2) {
        s1 += st[tid * 8 + t2];
        s2 += st[1024 + tid * 8 + t2];
      }
      int c = col0 + tid;
      if (c < Mp) {
        atomicAdd(&sums[c], s1);
        atomicAdd(&sums[Mp + c], s2);
      }
    }
  } else {
#pragma unroll
    for (int n = 0; n < 4; ++n) {
      int col = col0 + wc * 64 + n * 16 + l16;
      if (col >= Mp) continue;
      bool isL = col < M;
      int colR = col - M;
#pragma unroll
      for (int m = 0; m < 4; ++m)
#pragma unroll
        for (int i = 0; i < 4; ++i) {
          int row = row0 + wr * 64 + m * 16 + lr + i;
          if (row < N) {
            float v = acc[m][n][i];
            if (isL) OutL[(size_t)row * M + col] = bf16rne(v);
            else     OutR[(size_t)row * M + colR] = v;
          }
        }
    }
  }
}

// ---------------- combine (L2-4) ----------------
// y = mean_nbrs(bf16 Zl[src]) + Zr + bias_all + (deg>0 ? bias_deg : 0).
// G = lanes per node (each lane owns 4 consecutive cols, ushort4 gathers).
// PACK=1: write packed hi/lo fragment-planar; else fp32 out (row stride M).
template <int G, int LOGG, int M, int RELU, int STATS, int PACK>
__global__ __launch_bounds__(256) void combine(
    const ushort* __restrict__ Zl, const float* __restrict__ Zr,
    const int* __restrict__ adj, const int* __restrict__ offs,
    const int* __restrict__ cnt, const float* __restrict__ inv,
    const float* __restrict__ bias2, float* __restrict__ outF,
    ushort* __restrict__ outP, float* __restrict__ sums, int N) {
  constexpr int S = 256 / G;
  const int tid = threadIdx.x;
  const int c4 = (tid & (G - 1)) * 4;
  const int sub = tid >> LOGG;
  const bool act = (c4 < M);
  float ba0 = 0, ba1 = 0, ba2 = 0, ba3 = 0, bd0 = 0, bd1 = 0, bd2 = 0, bd3 = 0;
  if (act) {
    float4 ba = *(const float4*)&bias2[c4];
    float4 bd = *(const float4*)&bias2[M + c4];
    ba0 = ba.x; ba1 = ba.y; ba2 = ba.z; ba3 = ba.w;
    bd0 = bd.x; bd1 = bd.y; bd2 = bd.z; bd3 = bd.w;
  }
  float cs[4] = {0.f, 0.f, 0.f, 0.f}, cq[4] = {0.f, 0.f, 0.f, 0.f};
  const ushort* __restrict__ Zc = Zl + c4;
  for (int n = blockIdx.x * S + sub; n < N; n += gridDim.x * S) {
    if (act) {
      int off = offs[n], deg = cnt[n];
      float s0 = 0.f, s1 = 0.f, s2 = 0.f, s3 = 0.f;
      int i = 0;
      for (; i + 4 <= deg; i += 4) {
        int a0 = adj[off + i + 0];
        int a1 = adj[off + i + 1];
        int a2 = adj[off + i + 2];
        int a3 = adj[off + i + 3];
        ushort4 v0 = *(const ushort4*)&Zc[(size_t)a0 * M];
        ushort4 v1 = *(const ushort4*)&Zc[(size_t)a1 * M];
        ushort4 v2 = *(const ushort4*)&Zc[(size_t)a2 * M];
        ushort4 v3 = *(const ushort4*)&Zc[(size_t)a3 * M];
        s0 += (bf2f(v0.x) + bf2f(v1.x)) + (bf2f(v2.x) + bf2f(v3.x));
        s1 += (bf2f(v0.y) + bf2f(v1.y)) + (bf2f(v2.y) + bf2f(v3.y));
        s2 += (bf2f(v0.z) + bf2f(v1.z)) + (bf2f(v2.z) + bf2f(v3.z));
        s3 += (bf2f(v0.w) + bf2f(v1.w)) + (bf2f(v2.w) + bf2f(v3.w));
      }
      for (; i < deg; ++i) {
        ushort4 v = *(const ushort4*)&Zc[(size_t)adj[off + i] * M];
        s0 += bf2f(v.x); s1 += bf2f(v.y); s2 += bf2f(v.z); s3 += bf2f(v.w);
      }
      float invn = inv[n];
      float4 zr = *(const float4*)&Zr[(size_t)n * M + c4];
      float y0 = fmaf(s0, invn, zr.x + ba0);
      float y1 = fmaf(s1, invn, zr.y + ba1);
      float y2 = fmaf(s2, invn, zr.z + ba2);
      float y3 = fmaf(s3, invn, zr.w + ba3);
      if (deg > 0) { y0 += bd0; y1 += bd1; y2 += bd2; y3 += bd3; }
      if (RELU) {
        y0 = fmaxf(y0, 0.f); y1 = fmaxf(y1, 0.f);
        y2 = fmaxf(y2, 0.f); y3 = fmaxf(y3, 0.f);
      }
      if (PACK) {
        ushort4 H, L;
        H.x = bf16rne(y0); L.x = bf16rne(y0 - bf2f(H.x));
        H.y = bf16rne(y1); L.y = bf16rne(y1 - bf2f(H.y));
        H.z = bf16rne(y2); L.z = bf16rne(y2 - bf2f(H.z));
        H.w = bf16rne(y3); L.w = bf16rne(y3 - bf2f(H.w));
        const int kb = c4 >> 3, sl = c4 & 7;
        size_t chunk = ((size_t)(kb * 2) * NP + n) * 8 + sl;
        *(ushort4*)&outP[chunk] = H;
        *(ushort4*)&outP[chunk + (size_t)NP * 8] = L;
      } else {
        *(float4*)&outF[(size_t)n * M + c4] = make_float4(y0, y1, y2, y3);
      }
      if (STATS) {
        cs[0] += y0; cs[1] += y1; cs[2] += y2; cs[3] += y3;
        cq[0] += y0 * y0; cq[1] += y1 * y1; cq[2] += y2 * y2; cq[3] += y3 * y3;
      }
    }
  }
  if (STATS) {
    __shared__ float st1[S * M], st2[S * M];
#pragma unroll
    for (int j = 0; j < 4; ++j) {
      st1[sub * M + c4 + j] = cs[j];
      st2[sub * M + c4 + j] = cq[j];
    }
    __syncthreads();
    if (tid < M) {
      float s1 = 0.f, s2 = 0.f;
#pragma unroll
      for (int t2 = 0; t2 < S; ++t2) {
        s1 += st1[t2 * M + tid];
        s2 += st2[t2 * M + tid];
      }
      atomicAdd(&sums[tid], s1);
      atomicAdd(&sums[M + tid], s2);
    }
  }
}

__global__ void bn_affine(float* __restrict__ sums, const float* __restrict__ g,
                          const float* __restrict__ be, float* __restrict__ ab,
                          int M, float invN) {
  int j = threadIdx.x;
  if (j < M) {
    float s1 = sums[j], s2 = sums[M + j];
    float mu = s1 * invN;
    float var = fmaf(-mu, mu, s2 * invN);
    float a = g[j] / sqrtf(var + 1e-5f);
    ab[j] = a;
    ab[M + j] = fmaf(-mu, a, be[j]);
    sums[j] = 0.f;
    sums[M + j] = 0.f;
  }
}

extern "C" void kernel_launch(void* const* d_in, const int* in_sizes, int n_in,
                              void* d_out, int out_size, void* d_ws, size_t ws_size,
                              hipStream_t stream) {
  const int N = NN, E = NE;
  const float* x = (const float*)d_in[0];
  const int* ei = (const int*)d_in[1];
  const int* srcs = ei;
  const int* dsts = ei + E;

  const float* Wl1 = (const float*)d_in[2];
  const float* bl1 = (const float*)d_in[3];
  const float* Wr1 = (const float*)d_in[4];
  const float* Ws1 = (const float*)d_in[5];
  const float* bs1 = (const float*)d_in[6];
  const float* g1  = (const float*)d_in[7];
  const float* be1 = (const float*)d_in[8];
  const float* Wl2 = (const float*)d_in[9];
  const float* bl2 = (const float*)d_in[10];
  const float* Wr2 = (const float*)d_in[11];
  const float* Ws2 = (const float*)d_in[12];
  const float* bs2 = (const float*)d_in[13];
  const float* g2  = (const float*)d_in[14];
  const float* be2 = (const float*)d_in[15];
  const float* Wl3 = (const float*)d_in[16];
  const float* bl3 = (const float*)d_in[17];
  const float* Wr3 = (const float*)d_in[18];
  const float* Ws3 = (const float*)d_in[19];
  const float* bs3 = (const float*)d_in[20];
  const float* g3  = (const float*)d_in[21];
  const float* be3 = (const float*)d_in[22];
  const float* Wl4 = (const float*)d_in[23];
  const float* bl4 = (const float*)d_in[24];
  const float* Wr4 = (const float*)d_in[25];
  const float* Ws4 = (const float*)d_in[26];
  const float* bs4 = (const float*)d_in[27];

  // ---- workspace map (~116 MB) ----
  // A: hAP (K=256 packed, 51.25MB); hCP (K=64) aliases.
  // B: xP (K=128 packed, 25.62MB); hBP aliases.
  // C: aggP (25.62MB); Zr fp32 (max 25.6MB) aliases.
  // D: xb bf16 NP*128 (12.81MB); Zl bf16 (max 12.8MB) aliases.
  char* wsB = (char*)d_ws;
  ushort* hAP = (ushort*)wsB;
  ushort* hCP = hAP;
  ushort* xP  = (ushort*)(wsB + 51249152);
  ushort* hBP = xP;
  char* regC  = wsB + 51249152 + 25624576;
  ushort* aggP = (ushort*)regC;
  float* Zr   = (float*)regC;
  char* regD  = regC + 25624576;
  ushort* xb  = (ushort*)regD;
  ushort* Zl  = (ushort*)regD;
  char* p = regD + (size_t)NP * 128 * 2;
  ushort* W1p = (ushort*)p; p += 262144;
  ushort* W2p = (ushort*)p; p += 262144;
  ushort* W3p = (ushort*)p; p += 65536;
  ushort* W4p = (ushort*)p; p += 32768;
  float* sums = (float*)p; p += 512 * 4;
  float* ab   = (float*)p; p += 512 * 4;
  float* bias2 = (float*)p; p += 256 * 4;
  float* invc = (float*)p; p += (size_t)N * 4;
  int* cnt    = (int*)p; p += (size_t)N * 4;
  int* offs   = (int*)p; p += (size_t)N * 4;
  int* cursor = (int*)p; p += (size_t)N * 4;
  int* btot   = (int*)p; p += 256;
  int* adj    = (int*)p;

  hipMemsetAsync(cnt, 0, sizeof(int) * N, stream);
  int eb = (E + 255) / 256;
  int nb = (N + 1023) / 1024;  // 49
  count_deg<<<eb, 256, 0, stream>>>(dsts, cnt, E);
  scan_block<<<nb, 1024, 0, stream>>>(cnt, offs, btot, N);
  scan_tops<<<1, 64, 0, stream>>>(btot, nb);
  finalize_csr<<<(N + 255) / 256, 256, 0, stream>>>(offs, btot, cnt, cursor, invc, N);
  fill_adj<<<eb, 256, 0, stream>>>(srcs, dsts, cursor, adj, E);

  pack_x<<<NP * 16 / 256, 256, 0, stream>>>(x, xP, xb, N);
  prep_w<1><<<32 * 256 / 256, 256, 0, stream>>>(Wl1, Wr1, Ws1, nullptr, W1p,
                                                256, 128, 256, 256, 256);

  const int RB = NP / 128;  // 391
  const float invN = 1.0f / (float)N;

  // L1: aggregate bf16(x) (packed out), then [aggP|xP] @ W1p -> hAP
  aggregate1<<<NP / 8, 256, 0, stream>>>(xb, adj, offs, cnt, invc, aggP, sums, N);
  gemm_pk<1, 1, 8, 128><<<dim3(RB, 2), 256, 0, stream>>>(
      aggP, xP, W1p, bl1, bs1, nullptr, nullptr, hAP, sums, N, 256, 256, 256);
  bn_affine<<<1, 256, 0, stream>>>(sums, g1, be1, ab, 256, invN);

  // L2: Z = hA @ diag(a1)[Wl2|Wr2+Ws2] -> Zl bf16 + Zr fp32; combine -> hBP
  prep_w<0><<<32 * 256 / 256, 256, 0, stream>>>(Wl2, Wr2, Ws2, ab, W2p,
                                                256, 0, 128, 256, 256);
  prep_bias<<<128, 256, 0, stream>>>(Wl2, Wr2, Ws2, bl2, bs2, ab, bias2, 256, 128);
  gemm_pk<0, 0, 8, 0><<<dim3(RB, 2), 256, 0, stream>>>(
      hAP, nullptr, W2p, nullptr, nullptr, Zl, Zr, nullptr, nullptr, N, 128, 256, 256);
  combine<32, 5, 128, 1, 1, 1><<<2048, 256, 0, stream>>>(
      Zl, Zr, adj, offs, cnt, invc, bias2, nullptr, hBP, sums, N);
  bn_affine<<<1, 128, 0, stream>>>(sums, g2, be2, ab, 128, invN);

  // L3
  prep_w<0><<<16 * 128 / 256, 256, 0, stream>>>(Wl3, Wr3, Ws3, ab, W3p,
                                                128, 0, 64, 128, 128);
  prep_bias<<<64, 256, 0, stream>>>(Wl3, Wr3, Ws3, bl3, bs3, ab, bias2, 128, 64);
  gemm_pk<0, 0, 4, 0><<<dim3(RB, 1), 256, 0, stream>>>(
      hBP, nullptr, W3p, nullptr, nullptr, Zl, Zr, nullptr, nullptr, N, 64, 128, 128);
  combine<16, 4, 64, 1, 1, 1><<<2048, 256, 0, stream>>>(
      Zl, Zr, adj, offs, cnt, invc, bias2, nullptr, hCP, sums, N);
  bn_affine<<<1, 64, 0, stream>>>(sums, g3, be3, ab, 64, invN);

  // L4: Mp=80 (Mpad=128, pad cols zeroed in prep_w)
  prep_w<0><<<8 * 128 / 256, 256, 0, stream>>>(Wl4, Wr4, Ws4, ab, W4p,
                                               64, 0, 40, 80, 128);
  prep_bias<<<40, 256, 0, stream>>>(Wl4, Wr4, Ws4, bl4, bs4, ab, bias2, 64, 40);
  gemm_pk<0, 0, 2, 0><<<dim3(RB, 1), 256, 0, stream>>>(
      hCP, nullptr, W4p, nullptr, nullptr, Zl, Zr, nullptr, nullptr, N, 40, 80, 128);
  combine<16, 4, 40, 0, 0, 0><<<2048, 256, 0, stream>>>(
      Zl, Zr, adj, offs, cnt, invc, bias2, (float*)d_out, nullptr, nullptr, N);
}

// Round 13
// 539.308 us; speedup vs baseline: 1.6266x; 1.0582x over previous
//
#include <hip/hip_runtime.h>

// GNN: 4x GraphSAGE(mean) + skip Linear + BN(1-3) + ReLU(1-3), fp32.
// N=50000 nodes, E=800000 edges, dims 128->256->128->64->40.
//
// Round 13 = round 12 resubmit (r12 bench was a GPU-acquisition timeout;
// the XCD-partitioned gather experiment has never run).
// Gathers are L2-MISS-latency bound (r11: 8B/lane gathers gave only -22%;
// table 12.8MB >> 4MB per-XCD L2; FETCH 95MB @ 1.16 TB/s).
// Fix: column-blocked gather tables, 32 cols per pass (3.2MB, L2-resident),
// passes mapped to XCDs within ONE launch via pass=(blockIdx&7)&(NPASS-1):
// each XCD's private L2 caches only its pass's table slice.
//  - Zl / xb stored pass-blocked [p][row][32] (producers write directly).
//  - combineP: 8 lanes/node (ushort4), NPASS=4 (L2) / 2 (L3,L4).
//  - aggregate1p: NPASS=4 over x's 128 cols.
// Carried: BN folded into weights; packed bf16 hi/lo fragment-planar GEMM
// operands; gemm_pk no-LDS no-barrier (48 MFMA / K-32); Zr fp32 root half.

static constexpr int NN = 50000;
static constexpr int NE = 800000;
static constexpr int NP = 50048;   // rows padded to 128

typedef __attribute__((ext_vector_type(8))) short short8;
typedef __attribute__((ext_vector_type(4))) float f32x4;

static constexpr size_t PSTRIDE = (size_t)NP * 32;  // ushorts per pass-block

__device__ __forceinline__ unsigned short bf16rne(float x) {
  unsigned u = __float_as_uint(x);
  return (unsigned short)((u + 0x7FFFu + ((u >> 16) & 1u)) >> 16);
}
__device__ __forceinline__ float bf2f(unsigned short h) {
  return __uint_as_float(((unsigned)h) << 16);
}

// ---------------- CSR build ----------------
__global__ void count_deg(const int* __restrict__ dst, int* __restrict__ cnt, int E) {
  int e = blockIdx.x * blockDim.x + threadIdx.x;
  if (e < E) atomicAdd(&cnt[dst[e]], 1);
}

__global__ __launch_bounds__(1024) void scan_block(const int* __restrict__ cnt,
                                                   int* __restrict__ excl,
                                                   int* __restrict__ btot, int n) {
  __shared__ int lds[1024];
  int i = blockIdx.x * 1024 + threadIdx.x;
  int v = (i < n) ? cnt[i] : 0;
  lds[threadIdx.x] = v;
  __syncthreads();
#pragma unroll
  for (int off = 1; off < 1024; off <<= 1) {
    int t = 0;
    if ((int)threadIdx.x >= off) t = lds[threadIdx.x - off];
    __syncthreads();
    lds[threadIdx.x] += t;
    __syncthreads();
  }
  if (i < n) excl[i] = lds[threadIdx.x] - v;
  if (threadIdx.x == 1023) btot[blockIdx.x] = lds[1023];
}

__global__ void scan_tops(int* __restrict__ btot, int nb) {
  int t = threadIdx.x;
  int v = (t < nb) ? btot[t] : 0;
  int own = v;
#pragma unroll
  for (int off = 1; off < 64; off <<= 1) {
    int u = __shfl_up(v, off);
    if (t >= off) v += u;
  }
  if (t < nb) btot[t] = v - own;
}

__global__ void finalize_csr(int* __restrict__ offs, const int* __restrict__ btot,
                             const int* __restrict__ cnt, int* __restrict__ cursor,
                             float* __restrict__ inv, int n) {
  int i = blockIdx.x * blockDim.x + threadIdx.x;
  if (i < n) {
    int o = offs[i] + btot[i >> 10];
    offs[i] = o;
    cursor[i] = o;
    int c = cnt[i];
    inv[i] = 1.0f / (float)(c > 0 ? c : 1);
  }
}

__global__ void fill_adj(const int* __restrict__ src, const int* __restrict__ dst,
                         int* __restrict__ cursor, int* __restrict__ adj, int E) {
  int e = blockIdx.x * blockDim.x + threadIdx.x;
  if (e < E) {
    int p = atomicAdd(&cursor[dst[e]], 1);
    adj[p] = src[e];
  }
}

// ---------------- packing ----------------
// x -> packed hi/lo planes (xP) + pass-blocked bf16 copy xb[p][row][32].
__global__ void pack_x(const float* __restrict__ x, ushort* __restrict__ xP,
                       ushort* __restrict__ xb, int N) {
  int gid = blockIdx.x * 256 + threadIdx.x;
  int row = gid >> 4, kb = gid & 15;
  if (row >= NP) return;
  float v[8];
  if (row < N) {
    float4 a = *(const float4*)&x[(size_t)row * 128 + kb * 8];
    float4 b = *(const float4*)&x[(size_t)row * 128 + kb * 8 + 4];
    v[0]=a.x; v[1]=a.y; v[2]=a.z; v[3]=a.w; v[4]=b.x; v[5]=b.y; v[6]=b.z; v[7]=b.w;
  } else {
#pragma unroll
    for (int j = 0; j < 8; ++j) v[j] = 0.f;
  }
  short8 H, L;
#pragma unroll
  for (int j = 0; j < 8; ++j) {
    unsigned short h = bf16rne(v[j]);
    H[j] = (short)h;
    L[j] = (short)bf16rne(v[j] - bf2f(h));
  }
  *(short8*)&xP[((size_t)(kb * 2) * NP + row) * 8] = H;
  *(short8*)&xP[((size_t)(kb * 2 + 1) * NP + row) * 8] = L;
  *(short8*)&xb[(size_t)(kb >> 2) * PSTRIDE + (size_t)row * 32 + (kb & 3) * 8] = H;
}

// Pack weights in B-fragment layout, with optional BN fold (w *= a[k]).
template <int L1V>
__global__ void prep_w(const float* __restrict__ Wl, const float* __restrict__ Wr,
                       const float* __restrict__ Wsk, const float* __restrict__ ab,
                       ushort* __restrict__ Wp, int K, int K1, int M, int Mp, int Mpad) {
  int gid = blockIdx.x * 256 + threadIdx.x;
  int col = gid % Mpad, kb = gid / Mpad;
  if (kb >= (K >> 3)) return;
  short8 H, L;
#pragma unroll
  for (int j = 0; j < 8; ++j) {
    int k = kb * 8 + j;
    float v = 0.f;
    if (col < Mp) {
      if (L1V) {
        v = (k < K1) ? Wl[(size_t)k * M + col]
                     : Wr[(size_t)(k - K1) * M + col] + Wsk[(size_t)(k - K1) * M + col];
      } else {
        float w = (col < M) ? Wl[(size_t)k * M + col]
                            : Wr[(size_t)k * M + (col - M)] + Wsk[(size_t)k * M + (col - M)];
        v = ab[k] * w;
      }
    }
    unsigned short h = bf16rne(v);
    H[j] = (short)h;
    L[j] = (short)bf16rne(v - bf2f(h));
  }
  *(short8*)&Wp[((size_t)(kb * 2) * Mpad + col) * 8] = H;
  *(short8*)&Wp[((size_t)(kb * 2 + 1) * Mpad + col) * 8] = L;
}

// bias_all[c] = bl+bs+sum_k b[k](Wr+Ws)[k][c]; bias_deg[c] = sum_k b[k]Wl[k][c]
__global__ void prep_bias(const float* __restrict__ Wl, const float* __restrict__ Wr,
                          const float* __restrict__ Wsk, const float* __restrict__ bl,
                          const float* __restrict__ bs, const float* __restrict__ ab,
                          float* __restrict__ bias2, int K, int M) {
  int c = blockIdx.x;
  int k = threadIdx.x;
  float va = 0.f, vd = 0.f;
  if (k < K) {
    float b = ab[K + k];
    vd = b * Wl[(size_t)k * M + c];
    va = b * (Wr[(size_t)k * M + c] + Wsk[(size_t)k * M + c]);
  }
  __shared__ float r[512];
  r[k] = va;
  r[256 + k] = vd;
  __syncthreads();
  for (int off = 128; off > 0; off >>= 1) {
    if (k < off) {
      r[k] += r[k + off];
      r[256 + k] += r[256 + k + off];
    }
    __syncthreads();
  }
  if (k == 0) {
    bias2[c] = bl[c] + bs[c] + r[0];
    bias2[M + c] = r[256];
  }
}

// ---------------- aggregation (L1), XCD-partitioned column passes ----------
// mean of bf16(x) over nbrs; 4 passes x 32 cols; 8 lanes/node (ushort4).
// pass = (blockIdx&7)&3 -> each XCD's L2 holds one 3.2MB table slice.
__global__ __launch_bounds__(256) void aggregate1p(
    const ushort* __restrict__ xb, const int* __restrict__ adj,
    const int* __restrict__ offs, const int* __restrict__ cnt,
    const float* __restrict__ inv, ushort* __restrict__ aggP,
    float* __restrict__ sums, int N) {
  const int tid = threadIdx.x;
  if (blockIdx.x == 0) {
    for (int j = tid; j < 512; j += 256) sums[j] = 0.f;
  }
  const int xcd = blockIdx.x & 7;
  const int p = xcd & 3;
  const int setIdx = (blockIdx.x >> 3) * 2 + (xcd >> 2);
  const int nSets = (gridDim.x >> 3) * 2;
  const int sub = tid >> 3;          // 0..31
  const int c4 = (tid & 7) * 4;      // 0..28
  const int col = p * 32 + c4;       // 0..127
  const ushort* __restrict__ tab = xb + (size_t)p * PSTRIDE + c4;
  const int kb = col >> 3, sl = col & 7;

  for (int n = setIdx * 32 + sub; n < NP; n += nSets * 32) {
    float s0 = 0.f, s1 = 0.f, s2 = 0.f, s3 = 0.f, invn = 0.f;
    if (n < N) {
      invn = inv[n];
      int off = offs[n], deg = cnt[n];
      int i = 0;
      for (; i + 4 <= deg; i += 4) {
        int a0 = adj[off + i + 0];
        int a1 = adj[off + i + 1];
        int a2 = adj[off + i + 2];
        int a3 = adj[off + i + 3];
        ushort4 v0 = *(const ushort4*)&tab[(size_t)a0 * 32];
        ushort4 v1 = *(const ushort4*)&tab[(size_t)a1 * 32];
        ushort4 v2 = *(const ushort4*)&tab[(size_t)a2 * 32];
        ushort4 v3 = *(const ushort4*)&tab[(size_t)a3 * 32];
        s0 += (bf2f(v0.x) + bf2f(v1.x)) + (bf2f(v2.x) + bf2f(v3.x));
        s1 += (bf2f(v0.y) + bf2f(v1.y)) + (bf2f(v2.y) + bf2f(v3.y));
        s2 += (bf2f(v0.z) + bf2f(v1.z)) + (bf2f(v2.z) + bf2f(v3.z));
        s3 += (bf2f(v0.w) + bf2f(v1.w)) + (bf2f(v2.w) + bf2f(v3.w));
      }
      for (; i < deg; ++i) {
        ushort4 v = *(const ushort4*)&tab[(size_t)adj[off + i] * 32];
        s0 += bf2f(v.x); s1 += bf2f(v.y); s2 += bf2f(v.z); s3 += bf2f(v.w);
      }
    }
    float m0 = s0 * invn, m1 = s1 * invn, m2 = s2 * invn, m3 = s3 * invn;
    ushort4 H, L;
    H.x = bf16rne(m0); L.x = bf16rne(m0 - bf2f(H.x));
    H.y = bf16rne(m1); L.y = bf16rne(m1 - bf2f(H.y));
    H.z = bf16rne(m2); L.z = bf16rne(m2 - bf2f(H.z));
    H.w = bf16rne(m3); L.w = bf16rne(m3 - bf2f(H.w));
    size_t chunk = ((size_t)(kb * 2) * NP + n) * 8 + sl;
    *(ushort4*)&aggP[chunk] = H;
    *(ushort4*)&aggP[chunk + (size_t)NP * 8] = L;
  }
}

// ---------------- MFMA GEMM (no LDS, no barriers) ----------------
// C[N x Mp] = A @ B, A packed (TWO_A: [A1|A2] along K at KT1), B packed.
// EPI=1 (L1): +bias(bl+bs), relu, BN stats, PACKED output (OutP).
// EPI=0: Zl (cols<M) bf16 -> OutL pass-blocked [c>>5][row][c&31];
//        Zr (cols M..Mp) fp32 -> OutR (stride M).
template <int TWO_A, int EPI, int NK32, int KT1>
__global__ __launch_bounds__(256) void gemm_pk(
    const ushort* __restrict__ A1, const ushort* __restrict__ A2,
    const ushort* __restrict__ B, const float* __restrict__ bl,
    const float* __restrict__ bs, ushort* __restrict__ OutL,
    float* __restrict__ OutR, ushort* __restrict__ OutP,
    float* __restrict__ sums, int N, int M, int Mp, int Mpad) {
  const int tid = threadIdx.x;
  const int l = tid & 63;
  const int w = tid >> 6;
  const int wr = w >> 1, wc = w & 1;
  const int l16 = l & 15, lh = l >> 4;
  const int row0 = blockIdx.x * 128, col0 = blockIdx.y * 128;

  const f32x4 z4 = {0.f, 0.f, 0.f, 0.f};
  f32x4 acc[4][4];
#pragma unroll
  for (int m = 0; m < 4; ++m)
#pragma unroll
    for (int n = 0; n < 4; ++n) acc[m][n] = z4;

  const int arow = row0 + wr * 64 + l16;
  const int bcol = col0 + wc * 64 + l16;

#pragma unroll 2
  for (int it = 0; it < NK32; ++it) {
    const int kbase = it * 32;
    const ushort* Ap = A1;
    int kloc = kbase;
    if (TWO_A && kbase >= KT1) { Ap = A2; kloc = kbase - KT1; }
    const int akb = (kloc >> 3) + lh;
    const int bkb = (kbase >> 3) + lh;
    const ushort* a_hi = Ap + ((size_t)(akb * 2) * NP + arow) * 8;
    const ushort* a_lo = a_hi + (size_t)NP * 8;
    const ushort* b_hi = B + ((size_t)(bkb * 2) * Mpad + bcol) * 8;
    const ushort* b_lo = b_hi + (size_t)Mpad * 8;

    short8 ah[4], al[4], bh[4], blo[4];
#pragma unroll
    for (int m = 0; m < 4; ++m) {
      ah[m] = *(const short8*)(a_hi + m * 128);
      al[m] = *(const short8*)(a_lo + m * 128);
    }
#pragma unroll
    for (int n = 0; n < 4; ++n) {
      bh[n] = *(const short8*)(b_hi + n * 128);
      blo[n] = *(const short8*)(b_lo + n * 128);
    }
#pragma unroll
    for (int m = 0; m < 4; ++m)
#pragma unroll
      for (int n = 0; n < 4; ++n) {
        acc[m][n] = __builtin_amdgcn_mfma_f32_16x16x32_bf16(ah[m], bh[n], acc[m][n], 0, 0, 0);
        acc[m][n] = __builtin_amdgcn_mfma_f32_16x16x32_bf16(ah[m], blo[n], acc[m][n], 0, 0, 0);
        acc[m][n] = __builtin_amdgcn_mfma_f32_16x16x32_bf16(al[m], bh[n], acc[m][n], 0, 0, 0);
      }
  }

  const int lr = lh * 4;
  if (EPI) {
    __shared__ float st[2048];
    float cs[4] = {0.f, 0.f, 0.f, 0.f}, cq[4] = {0.f, 0.f, 0.f, 0.f};
#pragma unroll
    for (int n = 0; n < 4; ++n) {
      int col = col0 + wc * 64 + n * 16 + l16;
      bool cok = col < Mp;
      float bias = cok ? (bl[col] + bs[col]) : 0.f;
      int cb = col >> 3, ch = col & 7;
      size_t hbase = ((size_t)(cb * 2) * NP) * 8 + ch;
      size_t lbase = hbase + (size_t)NP * 8;
#pragma unroll
      for (int m = 0; m < 4; ++m)
#pragma unroll
        for (int i = 0; i < 4; ++i) {
          int row = row0 + wr * 64 + m * 16 + lr + i;
          float v = acc[m][n][i] + bias;
          v = fmaxf(v, 0.f);
          if (cok && row < N) {
            unsigned short hh = bf16rne(v);
            OutP[hbase + (size_t)row * 8] = hh;
            OutP[lbase + (size_t)row * 8] = bf16rne(v - bf2f(hh));
            cs[n] += v;
            cq[n] += v * v;
          }
        }
    }
    int slot = wr * 4 + lh;
#pragma unroll
    for (int n = 0; n < 4; ++n) {
      int c = wc * 64 + n * 16 + l16;
      st[c * 8 + slot] = cs[n];
      st[1024 + c * 8 + slot] = cq[n];
    }
    __syncthreads();
    if (tid < 128) {
      float s1 = 0.f, s2 = 0.f;
#pragma unroll
      for (int t2 = 0; t2 < 8; ++t2) {
        s1 += st[tid * 8 + t2];
        s2 += st[1024 + tid * 8 + t2];
      }
      int c = col0 + tid;
      if (c < Mp) {
        atomicAdd(&sums[c], s1);
        atomicAdd(&sums[Mp + c], s2);
      }
    }
  } else {
#pragma unroll
    for (int n = 0; n < 4; ++n) {
      int col = col0 + wc * 64 + n * 16 + l16;
      if (col >= Mp) continue;
      bool isL = col < M;
      int colR = col - M;
      size_t lblk = (size_t)(col >> 5) * PSTRIDE + (col & 31);
#pragma unroll
      for (int m = 0; m < 4; ++m)
#pragma unroll
        for (int i = 0; i < 4; ++i) {
          int row = row0 + wr * 64 + m * 16 + lr + i;
          if (row < N) {
            float v = acc[m][n][i];
            if (isL) OutL[lblk + (size_t)row * 32] = bf16rne(v);
            else     OutR[(size_t)row * M + colR] = v;
          }
        }
    }
  }
}

// ---------------- combine (L2-4), XCD-partitioned column passes ----------
// y = mean_nbrs(bf16 Zl[src]) + Zr + bias_all + (deg>0 ? bias_deg : 0).
// NPASS passes x 32 cols; 8 lanes/node (ushort4); Zl pass-blocked.
// pass = (blockIdx&7)&(NPASS-1) -> per-XCD L2-resident table slice.
template <int NPLOG, int M, int RELU, int STATS, int PACK>
__global__ __launch_bounds__(256) void combineP(
    const ushort* __restrict__ Zl, const float* __restrict__ Zr,
    const int* __restrict__ adj, const int* __restrict__ offs,
    const int* __restrict__ cnt, const float* __restrict__ inv,
    const float* __restrict__ bias2, float* __restrict__ outF,
    ushort* __restrict__ outP, float* __restrict__ sums, int N) {
  constexpr int NPASS = 1 << NPLOG;
  constexpr int XCDG = 8 >> NPLOG;
  const int tid = threadIdx.x;
  const int xcd = blockIdx.x & 7;
  const int p = xcd & (NPASS - 1);
  const int setIdx = (blockIdx.x >> 3) * XCDG + (xcd >> NPLOG);
  const int nSets = (gridDim.x >> 3) * XCDG;
  const int sub = tid >> 3;          // 0..31
  const int c4 = (tid & 7) * 4;      // 0..28
  const int col = p * 32 + c4;
  const bool act = col < M;

  float ba0 = 0, ba1 = 0, ba2 = 0, ba3 = 0, bd0 = 0, bd1 = 0, bd2 = 0, bd3 = 0;
  if (act) {
    float4 ba = *(const float4*)&bias2[col];
    float4 bd = *(const float4*)&bias2[M + col];
    ba0 = ba.x; ba1 = ba.y; ba2 = ba.z; ba3 = ba.w;
    bd0 = bd.x; bd1 = bd.y; bd2 = bd.z; bd3 = bd.w;
  }
  float cs[4] = {0.f, 0.f, 0.f, 0.f}, cq[4] = {0.f, 0.f, 0.f, 0.f};
  const ushort* __restrict__ tab = Zl + (size_t)p * PSTRIDE + c4;
  const int kb = col >> 3, sl = col & 7;

  for (int n = setIdx * 32 + sub; n < N; n += nSets * 32) {
    if (act) {
      int off = offs[n], deg = cnt[n];
      float s0 = 0.f, s1 = 0.f, s2 = 0.f, s3 = 0.f;
      int i = 0;
      for (; i + 4 <= deg; i += 4) {
        int a0 = adj[off + i + 0];
        int a1 = adj[off + i + 1];
        int a2 = adj[off + i + 2];
        int a3 = adj[off + i + 3];
        ushort4 v0 = *(const ushort4*)&tab[(size_t)a0 * 32];
        ushort4 v1 = *(const ushort4*)&tab[(size_t)a1 * 32];
        ushort4 v2 = *(const ushort4*)&tab[(size_t)a2 * 32];
        ushort4 v3 = *(const ushort4*)&tab[(size_t)a3 * 32];
        s0 += (bf2f(v0.x) + bf2f(v1.x)) + (bf2f(v2.x) + bf2f(v3.x));
        s1 += (bf2f(v0.y) + bf2f(v1.y)) + (bf2f(v2.y) + bf2f(v3.y));
        s2 += (bf2f(v0.z) + bf2f(v1.z)) + (bf2f(v2.z) + bf2f(v3.z));
        s3 += (bf2f(v0.w) + bf2f(v1.w)) + (bf2f(v2.w) + bf2f(v3.w));
      }
      for (; i < deg; ++i) {
        ushort4 v = *(const ushort4*)&tab[(size_t)adj[off + i] * 32];
        s0 += bf2f(v.x); s1 += bf2f(v.y); s2 += bf2f(v.z); s3 += bf2f(v.w);
      }
      float invn = inv[n];
      float4 zr = *(const float4*)&Zr[(size_t)n * M + col];
      float y0 = fmaf(s0, invn, zr.x + ba0);
      float y1 = fmaf(s1, invn, zr.y + ba1);
      float y2 = fmaf(s2, invn, zr.z + ba2);
      float y3 = fmaf(s3, invn, zr.w + ba3);
      if (deg > 0) { y0 += bd0; y1 += bd1; y2 += bd2; y3 += bd3; }
      if (RELU) {
        y0 = fmaxf(y0, 0.f); y1 = fmaxf(y1, 0.f);
        y2 = fmaxf(y2, 0.f); y3 = fmaxf(y3, 0.f);
      }
      if (PACK) {
        ushort4 H, L;
        H.x = bf16rne(y0); L.x = bf16rne(y0 - bf2f(H.x));
        H.y = bf16rne(y1); L.y = bf16rne(y1 - bf2f(H.y));
        H.z = bf16rne(y2); L.z = bf16rne(y2 - bf2f(H.z));
        H.w = bf16rne(y3); L.w = bf16rne(y3 - bf2f(H.w));
        size_t chunk = ((size_t)(kb * 2) * NP + n) * 8 + sl;
        *(ushort4*)&outP[chunk] = H;
        *(ushort4*)&outP[chunk + (size_t)NP * 8] = L;
      } else {
        *(float4*)&outF[(size_t)n * M + col] = make_float4(y0, y1, y2, y3);
      }
      if (STATS) {
        cs[0] += y0; cs[1] += y1; cs[2] += y2; cs[3] += y3;
        cq[0] += y0 * y0; cq[1] += y1 * y1; cq[2] += y2 * y2; cq[3] += y3 * y3;
      }
    }
  }
  if (STATS) {
    __shared__ float st1[32 * 32], st2[32 * 32];
#pragma unroll
    for (int j = 0; j < 4; ++j) {
      st1[sub * 32 + c4 + j] = cs[j];
      st2[sub * 32 + c4 + j] = cq[j];
    }
    __syncthreads();
    if (tid < 32) {
      float s1 = 0.f, s2 = 0.f;
#pragma unroll
      for (int t2 = 0; t2 < 32; ++t2) {
        s1 += st1[t2 * 32 + tid];
        s2 += st2[t2 * 32 + tid];
      }
      int c = p * 32 + tid;
      if (c < M) {
        atomicAdd(&sums[c], s1);
        atomicAdd(&sums[M + c], s2);
      }
    }
  }
}

__global__ void bn_affine(float* __restrict__ sums, const float* __restrict__ g,
                          const float* __restrict__ be, float* __restrict__ ab,
                          int M, float invN) {
  int j = threadIdx.x;
  if (j < M) {
    float s1 = sums[j], s2 = sums[M + j];
    float mu = s1 * invN;
    float var = fmaf(-mu, mu, s2 * invN);
    float a = g[j] / sqrtf(var + 1e-5f);
    ab[j] = a;
    ab[M + j] = fmaf(-mu, a, be[j]);
    sums[j] = 0.f;
    sums[M + j] = 0.f;
  }
}

extern "C" void kernel_launch(void* const* d_in, const int* in_sizes, int n_in,
                              void* d_out, int out_size, void* d_ws, size_t ws_size,
                              hipStream_t stream) {
  const int N = NN, E = NE;
  const float* x = (const float*)d_in[0];
  const int* ei = (const int*)d_in[1];
  const int* srcs = ei;
  const int* dsts = ei + E;

  const float* Wl1 = (const float*)d_in[2];
  const float* bl1 = (const float*)d_in[3];
  const float* Wr1 = (const float*)d_in[4];
  const float* Ws1 = (const float*)d_in[5];
  const float* bs1 = (const float*)d_in[6];
  const float* g1  = (const float*)d_in[7];
  const float* be1 = (const float*)d_in[8];
  const float* Wl2 = (const float*)d_in[9];
  const float* bl2 = (const float*)d_in[10];
  const float* Wr2 = (const float*)d_in[11];
  const float* Ws2 = (const float*)d_in[12];
  const float* bs2 = (const float*)d_in[13];
  const float* g2  = (const float*)d_in[14];
  const float* be2 = (const float*)d_in[15];
  const float* Wl3 = (const float*)d_in[16];
  const float* bl3 = (const float*)d_in[17];
  const float* Wr3 = (const float*)d_in[18];
  const float* Ws3 = (const float*)d_in[19];
  const float* bs3 = (const float*)d_in[20];
  const float* g3  = (const float*)d_in[21];
  const float* be3 = (const float*)d_in[22];
  const float* Wl4 = (const float*)d_in[23];
  const float* bl4 = (const float*)d_in[24];
  const float* Wr4 = (const float*)d_in[25];
  const float* Ws4 = (const float*)d_in[26];
  const float* bs4 = (const float*)d_in[27];

  // ---- workspace map (~116 MB) ----
  // A: hAP (K=256 packed, 51.25MB); hCP (K=64) aliases.
  // B: xP (K=128 packed, 25.62MB); hBP aliases.
  // C: aggP (25.62MB); Zr fp32 (max 25.6MB) aliases.
  // D: xb blocked [4][NP][32] (12.81MB); Zl blocked (max 4 passes) aliases.
  char* wsB = (char*)d_ws;
  ushort* hAP = (ushort*)wsB;
  ushort* hCP = hAP;
  ushort* xP  = (ushort*)(wsB + 51249152);
  ushort* hBP = xP;
  char* regC  = wsB + 51249152 + 25624576;
  ushort* aggP = (ushort*)regC;
  float* Zr   = (float*)regC;
  char* regD  = regC + 25624576;
  ushort* xb  = (ushort*)regD;
  ushort* Zl  = (ushort*)regD;
  char* p = regD + (size_t)NP * 128 * 2;
  ushort* W1p = (ushort*)p; p += 262144;
  ushort* W2p = (ushort*)p; p += 262144;
  ushort* W3p = (ushort*)p; p += 65536;
  ushort* W4p = (ushort*)p; p += 32768;
  float* sums = (float*)p; p += 512 * 4;
  float* ab   = (float*)p; p += 512 * 4;
  float* bias2 = (float*)p; p += 256 * 4;
  float* invc = (float*)p; p += (size_t)N * 4;
  int* cnt    = (int*)p; p += (size_t)N * 4;
  int* offs   = (int*)p; p += (size_t)N * 4;
  int* cursor = (int*)p; p += (size_t)N * 4;
  int* btot   = (int*)p; p += 256;
  int* adj    = (int*)p;

  hipMemsetAsync(cnt, 0, sizeof(int) * N, stream);
  int eb = (E + 255) / 256;
  int nb = (N + 1023) / 1024;  // 49
  count_deg<<<eb, 256, 0, stream>>>(dsts, cnt, E);
  scan_block<<<nb, 1024, 0, stream>>>(cnt, offs, btot, N);
  scan_tops<<<1, 64, 0, stream>>>(btot, nb);
  finalize_csr<<<(N + 255) / 256, 256, 0, stream>>>(offs, btot, cnt, cursor, invc, N);
  fill_adj<<<eb, 256, 0, stream>>>(srcs, dsts, cursor, adj, E);

  pack_x<<<NP * 16 / 256, 256, 0, stream>>>(x, xP, xb, N);
  prep_w<1><<<32 * 256 / 256, 256, 0, stream>>>(Wl1, Wr1, Ws1, nullptr, W1p,
                                                256, 128, 256, 256, 256);

  const int RB = NP / 128;  // 391
  const int GP = 4096;      // pass-partitioned gather grid (multiple of 8)
  const float invN = 1.0f / (float)N;

  // L1: aggregate bf16(x) (4 XCD-passes), then [aggP|xP] @ W1p -> hAP
  aggregate1p<<<GP, 256, 0, stream>>>(xb, adj, offs, cnt, invc, aggP, sums, N);
  gemm_pk<1, 1, 8, 128><<<dim3(RB, 2), 256, 0, stream>>>(
      aggP, xP, W1p, bl1, bs1, nullptr, nullptr, hAP, sums, N, 256, 256, 256);
  bn_affine<<<1, 256, 0, stream>>>(sums, g1, be1, ab, 256, invN);

  // L2: Z = hA @ diag(a1)[Wl2|Wr2+Ws2] -> Zl blocked bf16 + Zr fp32; combine
  prep_w<0><<<32 * 256 / 256, 256, 0, stream>>>(Wl2, Wr2, Ws2, ab, W2p,
                                                256, 0, 128, 256, 256);
  prep_bias<<<128, 256, 0, stream>>>(Wl2, Wr2, Ws2, bl2, bs2, ab, bias2, 256, 128);
  gemm_pk<0, 0, 8, 0><<<dim3(RB, 2), 256, 0, stream>>>(
      hAP, nullptr, W2p, nullptr, nullptr, Zl, Zr, nullptr, nullptr, N, 128, 256, 256);
  combineP<2, 128, 1, 1, 1><<<GP, 256, 0, stream>>>(
      Zl, Zr, adj, offs, cnt, invc, bias2, nullptr, hBP, sums, N);
  bn_affine<<<1, 128, 0, stream>>>(sums, g2, be2, ab, 128, invN);

  // L3
  prep_w<0><<<16 * 128 / 256, 256, 0, stream>>>(Wl3, Wr3, Ws3, ab, W3p,
                                                128, 0, 64, 128, 128);
  prep_bias<<<64, 256, 0, stream>>>(Wl3, Wr3, Ws3, bl3, bs3, ab, bias2, 128, 64);
  gemm_pk<0, 0, 4, 0><<<dim3(RB, 1), 256, 0, stream>>>(
      hBP, nullptr, W3p, nullptr, nullptr, Zl, Zr, nullptr, nullptr, N, 64, 128, 128);
  combineP<1, 64, 1, 1, 1><<<GP, 256, 0, stream>>>(
      Zl, Zr, adj, offs, cnt, invc, bias2, nullptr, hCP, sums, N);
  bn_affine<<<1, 64, 0, stream>>>(sums, g3, be3, ab, 64, invN);

  // L4: Mp=80 (Mpad=128, pad cols zeroed in prep_w); 2 passes (cols 0-31, 32-39)
  prep_w<0><<<8 * 128 / 256, 256, 0, stream>>>(Wl4, Wr4, Ws4, ab, W4p,
                                               64, 0, 40, 80, 128);
  prep_bias<<<40, 256, 0, stream>>>(Wl4, Wr4, Ws4, bl4, bs4, ab, bias2, 64, 40);
  gemm_pk<0, 0, 2, 0><<<dim3(RB, 1), 256, 0, stream>>>(
      hCP, nullptr, W4p, nullptr, nullptr, Zl, Zr, nullptr, nullptr, N, 40, 80, 128);
  combineP<1, 40, 0, 0, 0><<<GP, 256, 0, stream>>>(
      Zl, Zr, adj, offs, cnt, invc, bias2, (float*)d_out, nullptr, nullptr, N);
}

// Round 14
// 527.177 us; speedup vs baseline: 1.6640x; 1.0230x over previous
//
#include <hip/hip_runtime.h>

// GNN: 4x GraphSAGE(mean) + skip Linear + BN(1-3) + ReLU(1-3), fp32.
// N=50000 nodes, E=800000 edges, dims 128->256->128->64->40.
//
// Round 14: gathers are L2-HIT-latency bound (r13: XCD-partitioned passes
// cut FETCH 95->31MB but combineP only -20%; VALUBusy 11% = dependent
// adj->gather chain). Break the chain:
//  - coalesced adj load (lane k reads adj[off+i+k]) + __shfl broadcast
//    -> 8 INDEPENDENT gathers in flight per 8-neighbor step.
//  - CSR padded per-node to multiple of 8 with dummy index N; gather
//    tables zero rows >= N (pack_x already did; gemm_pk now writes zeros)
//    -> pure 8-wide loop, no serial tail. Zeros are exact.
// Carried: XCD-partitioned 32-col pass gathers (pass=(blockIdx&7)&(NPASS-1),
// 3.2MB L2-resident slices); BN folded into weights; packed bf16 hi/lo
// fragment-planar GEMM; gemm_pk no-LDS no-barrier; Zl bf16 + Zr fp32.

static constexpr int NN = 50000;
static constexpr int NE = 800000;
static constexpr int NP = 50048;   // rows padded to 128
static constexpr int NADJ = NE + 7 * NN;  // padded adjacency capacity

typedef __attribute__((ext_vector_type(8))) short short8;
typedef __attribute__((ext_vector_type(4))) float f32x4;

static constexpr size_t PSTRIDE = (size_t)NP * 32;  // ushorts per pass-block

__device__ __forceinline__ unsigned short bf16rne(float x) {
  unsigned u = __float_as_uint(x);
  return (unsigned short)((u + 0x7FFFu + ((u >> 16) & 1u)) >> 16);
}
__device__ __forceinline__ float bf2f(unsigned short h) {
  return __uint_as_float(((unsigned)h) << 16);
}

// ---------------- CSR build (padded to 8 per node) ----------------
__global__ void count_deg(const int* __restrict__ dst, int* __restrict__ cnt, int E) {
  int e = blockIdx.x * blockDim.x + threadIdx.x;
  if (e < E) atomicAdd(&cnt[dst[e]], 1);
}

__global__ __launch_bounds__(1024) void scan_block(const int* __restrict__ cnt,
                                                   int* __restrict__ excl,
                                                   int* __restrict__ btot, int n) {
  __shared__ int lds[1024];
  int i = blockIdx.x * 1024 + threadIdx.x;
  int v = (i < n) ? ((cnt[i] + 7) & ~7) : 0;  // PADDED degree
  lds[threadIdx.x] = v;
  __syncthreads();
#pragma unroll
  for (int off = 1; off < 1024; off <<= 1) {
    int t = 0;
    if ((int)threadIdx.x >= off) t = lds[threadIdx.x - off];
    __syncthreads();
    lds[threadIdx.x] += t;
    __syncthreads();
  }
  if (i < n) excl[i] = lds[threadIdx.x] - v;
  if (threadIdx.x == 1023) btot[blockIdx.x] = lds[1023];
}

__global__ void scan_tops(int* __restrict__ btot, int nb) {
  int t = threadIdx.x;
  int v = (t < nb) ? btot[t] : 0;
  int own = v;
#pragma unroll
  for (int off = 1; off < 64; off <<= 1) {
    int u = __shfl_up(v, off);
    if (t >= off) v += u;
  }
  if (t < nb) btot[t] = v - own;
}

__global__ void finalize_csr(int* __restrict__ offs, const int* __restrict__ btot,
                             const int* __restrict__ cnt, int* __restrict__ cursor,
                             float* __restrict__ inv, int n) {
  int i = blockIdx.x * blockDim.x + threadIdx.x;
  if (i < n) {
    int o = offs[i] + btot[i >> 10];
    offs[i] = o;
    cursor[i] = o;
    int c = cnt[i];
    inv[i] = 1.0f / (float)(c > 0 ? c : 1);
  }
}

__global__ void fill_dummy(int* __restrict__ adj, int n) {
  int i = blockIdx.x * blockDim.x + threadIdx.x;
  if (i < n) adj[i] = NN;  // dummy -> zero row in gather tables
}

__global__ void fill_adj(const int* __restrict__ src, const int* __restrict__ dst,
                         int* __restrict__ cursor, int* __restrict__ adj, int E) {
  int e = blockIdx.x * blockDim.x + threadIdx.x;
  if (e < E) {
    int p = atomicAdd(&cursor[dst[e]], 1);
    adj[p] = src[e];
  }
}

// ---------------- packing ----------------
// x -> packed hi/lo planes (xP) + pass-blocked bf16 copy xb[p][row][32].
__global__ void pack_x(const float* __restrict__ x, ushort* __restrict__ xP,
                       ushort* __restrict__ xb, int N) {
  int gid = blockIdx.x * 256 + threadIdx.x;
  int row = gid >> 4, kb = gid & 15;
  if (row >= NP) return;
  float v[8];
  if (row < N) {
    float4 a = *(const float4*)&x[(size_t)row * 128 + kb * 8];
    float4 b = *(const float4*)&x[(size_t)row * 128 + kb * 8 + 4];
    v[0]=a.x; v[1]=a.y; v[2]=a.z; v[3]=a.w; v[4]=b.x; v[5]=b.y; v[6]=b.z; v[7]=b.w;
  } else {
#pragma unroll
    for (int j = 0; j < 8; ++j) v[j] = 0.f;
  }
  short8 H, L;
#pragma unroll
  for (int j = 0; j < 8; ++j) {
    unsigned short h = bf16rne(v[j]);
    H[j] = (short)h;
    L[j] = (short)bf16rne(v[j] - bf2f(h));
  }
  *(short8*)&xP[((size_t)(kb * 2) * NP + row) * 8] = H;
  *(short8*)&xP[((size_t)(kb * 2 + 1) * NP + row) * 8] = L;
  *(short8*)&xb[(size_t)(kb >> 2) * PSTRIDE + (size_t)row * 32 + (kb & 3) * 8] = H;
}

// Pack weights in B-fragment layout, with optional BN fold (w *= a[k]).
template <int L1V>
__global__ void prep_w(const float* __restrict__ Wl, const float* __restrict__ Wr,
                       const float* __restrict__ Wsk, const float* __restrict__ ab,
                       ushort* __restrict__ Wp, int K, int K1, int M, int Mp, int Mpad) {
  int gid = blockIdx.x * 256 + threadIdx.x;
  int col = gid % Mpad, kb = gid / Mpad;
  if (kb >= (K >> 3)) return;
  short8 H, L;
#pragma unroll
  for (int j = 0; j < 8; ++j) {
    int k = kb * 8 + j;
    float v = 0.f;
    if (col < Mp) {
      if (L1V) {
        v = (k < K1) ? Wl[(size_t)k * M + col]
                     : Wr[(size_t)(k - K1) * M + col] + Wsk[(size_t)(k - K1) * M + col];
      } else {
        float w = (col < M) ? Wl[(size_t)k * M + col]
                            : Wr[(size_t)k * M + (col - M)] + Wsk[(size_t)k * M + (col - M)];
        v = ab[k] * w;
      }
    }
    unsigned short h = bf16rne(v);
    H[j] = (short)h;
    L[j] = (short)bf16rne(v - bf2f(h));
  }
  *(short8*)&Wp[((size_t)(kb * 2) * Mpad + col) * 8] = H;
  *(short8*)&Wp[((size_t)(kb * 2 + 1) * Mpad + col) * 8] = L;
}

// bias_all[c] = bl+bs+sum_k b[k](Wr+Ws)[k][c]; bias_deg[c] = sum_k b[k]Wl[k][c]
__global__ void prep_bias(const float* __restrict__ Wl, const float* __restrict__ Wr,
                          const float* __restrict__ Wsk, const float* __restrict__ bl,
                          const float* __restrict__ bs, const float* __restrict__ ab,
                          float* __restrict__ bias2, int K, int M) {
  int c = blockIdx.x;
  int k = threadIdx.x;
  float va = 0.f, vd = 0.f;
  if (k < K) {
    float b = ab[K + k];
    vd = b * Wl[(size_t)k * M + c];
    va = b * (Wr[(size_t)k * M + c] + Wsk[(size_t)k * M + c]);
  }
  __shared__ float r[512];
  r[k] = va;
  r[256 + k] = vd;
  __syncthreads();
  for (int off = 128; off > 0; off >>= 1) {
    if (k < off) {
      r[k] += r[k + off];
      r[256 + k] += r[256 + k + off];
    }
    __syncthreads();
  }
  if (k == 0) {
    bias2[c] = bl[c] + bs[c] + r[0];
    bias2[M + c] = r[256];
  }
}

// 8-wide gather step: coalesced adj + shfl broadcast + 8 independent gathers.
#define GATHER8(tab, base)                                                    \
  {                                                                           \
    int aj = adj[base + k8];                                                  \
    int a0 = __shfl(aj, gb + 0), a1 = __shfl(aj, gb + 1);                     \
    int a2 = __shfl(aj, gb + 2), a3 = __shfl(aj, gb + 3);                     \
    int a4 = __shfl(aj, gb + 4), a5 = __shfl(aj, gb + 5);                     \
    int a6 = __shfl(aj, gb + 6), a7 = __shfl(aj, gb + 7);                     \
    ushort4 v0 = *(const ushort4*)&tab[(size_t)a0 * 32];                      \
    ushort4 v1 = *(const ushort4*)&tab[(size_t)a1 * 32];                      \
    ushort4 v2 = *(const ushort4*)&tab[(size_t)a2 * 32];                      \
    ushort4 v3 = *(const ushort4*)&tab[(size_t)a3 * 32];                      \
    ushort4 v4 = *(const ushort4*)&tab[(size_t)a4 * 32];                      \
    ushort4 v5 = *(const ushort4*)&tab[(size_t)a5 * 32];                      \
    ushort4 v6 = *(const ushort4*)&tab[(size_t)a6 * 32];                      \
    ushort4 v7 = *(const ushort4*)&tab[(size_t)a7 * 32];                      \
    s0 += ((bf2f(v0.x) + bf2f(v1.x)) + (bf2f(v2.x) + bf2f(v3.x))) +          \
          ((bf2f(v4.x) + bf2f(v5.x)) + (bf2f(v6.x) + bf2f(v7.x)));           \
    s1 += ((bf2f(v0.y) + bf2f(v1.y)) + (bf2f(v2.y) + bf2f(v3.y))) +          \
          ((bf2f(v4.y) + bf2f(v5.y)) + (bf2f(v6.y) + bf2f(v7.y)));           \
    s2 += ((bf2f(v0.z) + bf2f(v1.z)) + (bf2f(v2.z) + bf2f(v3.z))) +          \
          ((bf2f(v4.z) + bf2f(v5.z)) + (bf2f(v6.z) + bf2f(v7.z)));           \
    s3 += ((bf2f(v0.w) + bf2f(v1.w)) + (bf2f(v2.w) + bf2f(v3.w))) +          \
          ((bf2f(v4.w) + bf2f(v5.w)) + (bf2f(v6.w) + bf2f(v7.w)));           \
  }

// ---------------- aggregation (L1), XCD-partitioned column passes ----------
__global__ __launch_bounds__(256) void aggregate1p(
    const ushort* __restrict__ xb, const int* __restrict__ adj,
    const int* __restrict__ offs, const int* __restrict__ cnt,
    const float* __restrict__ inv, ushort* __restrict__ aggP,
    float* __restrict__ sums, int N) {
  const int tid = threadIdx.x;
  if (blockIdx.x == 0) {
    for (int j = tid; j < 512; j += 256) sums[j] = 0.f;
  }
  const int xcd = blockIdx.x & 7;
  const int p = xcd & 3;
  const int setIdx = (blockIdx.x >> 3) * 2 + (xcd >> 2);
  const int nSets = (gridDim.x >> 3) * 2;
  const int lane = tid & 63;
  const int gb = lane & 56;
  const int k8 = lane & 7;
  const int sub = tid >> 3;          // 0..31
  const int c4 = (tid & 7) * 4;      // 0..28
  const int col = p * 32 + c4;       // 0..127
  const ushort* __restrict__ tab = xb + (size_t)p * PSTRIDE + c4;
  const int kb = col >> 3, sl = col & 7;

  for (int n = setIdx * 32 + sub; n < NP; n += nSets * 32) {
    float s0 = 0.f, s1 = 0.f, s2 = 0.f, s3 = 0.f, invn = 0.f;
    if (n < N) {   // group-uniform branch (shfl-safe)
      invn = inv[n];
      int off = offs[n];
      int pdeg = (cnt[n] + 7) & ~7;
      for (int i = 0; i < pdeg; i += 8) GATHER8(tab, off + i);
    }
    float m0 = s0 * invn, m1 = s1 * invn, m2 = s2 * invn, m3 = s3 * invn;
    ushort4 H, L;
    H.x = bf16rne(m0); L.x = bf16rne(m0 - bf2f(H.x));
    H.y = bf16rne(m1); L.y = bf16rne(m1 - bf2f(H.y));
    H.z = bf16rne(m2); L.z = bf16rne(m2 - bf2f(H.z));
    H.w = bf16rne(m3); L.w = bf16rne(m3 - bf2f(H.w));
    size_t chunk = ((size_t)(kb * 2) * NP + n) * 8 + sl;
    *(ushort4*)&aggP[chunk] = H;
    *(ushort4*)&aggP[chunk + (size_t)NP * 8] = L;
  }
}

// ---------------- MFMA GEMM (no LDS, no barriers) ----------------
// EPI=1 (L1): +bias, relu, BN stats, PACKED output (OutP).
// EPI=0: Zl bf16 pass-blocked (rows>=N ZEROED for dummy gathers); Zr fp32.
template <int TWO_A, int EPI, int NK32, int KT1>
__global__ __launch_bounds__(256) void gemm_pk(
    const ushort* __restrict__ A1, const ushort* __restrict__ A2,
    const ushort* __restrict__ B, const float* __restrict__ bl,
    const float* __restrict__ bs, ushort* __restrict__ OutL,
    float* __restrict__ OutR, ushort* __restrict__ OutP,
    float* __restrict__ sums, int N, int M, int Mp, int Mpad) {
  const int tid = threadIdx.x;
  const int l = tid & 63;
  const int w = tid >> 6;
  const int wr = w >> 1, wc = w & 1;
  const int l16 = l & 15, lh = l >> 4;
  const int row0 = blockIdx.x * 128, col0 = blockIdx.y * 128;

  const f32x4 z4 = {0.f, 0.f, 0.f, 0.f};
  f32x4 acc[4][4];
#pragma unroll
  for (int m = 0; m < 4; ++m)
#pragma unroll
    for (int n = 0; n < 4; ++n) acc[m][n] = z4;

  const int arow = row0 + wr * 64 + l16;
  const int bcol = col0 + wc * 64 + l16;

#pragma unroll 2
  for (int it = 0; it < NK32; ++it) {
    const int kbase = it * 32;
    const ushort* Ap = A1;
    int kloc = kbase;
    if (TWO_A && kbase >= KT1) { Ap = A2; kloc = kbase - KT1; }
    const int akb = (kloc >> 3) + lh;
    const int bkb = (kbase >> 3) + lh;
    const ushort* a_hi = Ap + ((size_t)(akb * 2) * NP + arow) * 8;
    const ushort* a_lo = a_hi + (size_t)NP * 8;
    const ushort* b_hi = B + ((size_t)(bkb * 2) * Mpad + bcol) * 8;
    const ushort* b_lo = b_hi + (size_t)Mpad * 8;

    short8 ah[4], al[4], bh[4], blo[4];
#pragma unroll
    for (int m = 0; m < 4; ++m) {
      ah[m] = *(const short8*)(a_hi + m * 128);
      al[m] = *(const short8*)(a_lo + m * 128);
    }
#pragma unroll
    for (int n = 0; n < 4; ++n) {
      bh[n] = *(const short8*)(b_hi + n * 128);
      blo[n] = *(const short8*)(b_lo + n * 128);
    }
#pragma unroll
    for (int m = 0; m < 4; ++m)
#pragma unroll
      for (int n = 0; n < 4; ++n) {
        acc[m][n] = __builtin_amdgcn_mfma_f32_16x16x32_bf16(ah[m], bh[n], acc[m][n], 0, 0, 0);
        acc[m][n] = __builtin_amdgcn_mfma_f32_16x16x32_bf16(ah[m], blo[n], acc[m][n], 0, 0, 0);
        acc[m][n] = __builtin_amdgcn_mfma_f32_16x16x32_bf16(al[m], bh[n], acc[m][n], 0, 0, 0);
      }
  }

  const int lr = lh * 4;
  if (EPI) {
    __shared__ float st[2048];
    float cs[4] = {0.f, 0.f, 0.f, 0.f}, cq[4] = {0.f, 0.f, 0.f, 0.f};
#pragma unroll
    for (int n = 0; n < 4; ++n) {
      int col = col0 + wc * 64 + n * 16 + l16;
      bool cok = col < Mp;
      float bias = cok ? (bl[col] + bs[col]) : 0.f;
      int cb = col >> 3, ch = col & 7;
      size_t hbase = ((size_t)(cb * 2) * NP) * 8 + ch;
      size_t lbase = hbase + (size_t)NP * 8;
#pragma unroll
      for (int m = 0; m < 4; ++m)
#pragma unroll
        for (int i = 0; i < 4; ++i) {
          int row = row0 + wr * 64 + m * 16 + lr + i;
          float v = acc[m][n][i] + bias;
          v = fmaxf(v, 0.f);
          if (cok && row < N) {
            unsigned short hh = bf16rne(v);
            OutP[hbase + (size_t)row * 8] = hh;
            OutP[lbase + (size_t)row * 8] = bf16rne(v - bf2f(hh));
            cs[n] += v;
            cq[n] += v * v;
          }
        }
    }
    int slot = wr * 4 + lh;
#pragma unroll
    for (int n = 0; n < 4; ++n) {
      int c = wc * 64 + n * 16 + l16;
      st[c * 8 + slot] = cs[n];
      st[1024 + c * 8 + slot] = cq[n];
    }
    __syncthreads();
    if (tid < 128) {
      float s1 = 0.f, s2 = 0.f;
#pragma unroll
      for (int t2 = 0; t2 < 8; ++t2) {
        s1 += st[tid * 8 + t2];
        s2 += st[1024 + tid * 8 + t2];
      }
      int c = col0 + tid;
      if (c < Mp) {
        atomicAdd(&sums[c], s1);
        atomicAdd(&sums[Mp + c], s2);
      }
    }
  } else {
#pragma unroll
    for (int n = 0; n < 4; ++n) {
      int col = col0 + wc * 64 + n * 16 + l16;
      if (col >= Mp) continue;
      bool isL = col < M;
      int colR = col - M;
      size_t lblk = (size_t)(col >> 5) * PSTRIDE + (col & 31);
#pragma unroll
      for (int m = 0; m < 4; ++m)
#pragma unroll
        for (int i = 0; i < 4; ++i) {
          int row = row0 + wr * 64 + m * 16 + lr + i;
          float v = acc[m][n][i];
          if (isL) {
            OutL[lblk + (size_t)row * 32] = (row < N) ? bf16rne(v) : (ushort)0;
          } else if (row < N) {
            OutR[(size_t)row * M + colR] = v;
          }
        }
    }
  }
}

// ---------------- combine (L2-4), XCD-partitioned column passes ----------
template <int NPLOG, int M, int RELU, int STATS, int PACK>
__global__ __launch_bounds__(256) void combineP(
    const ushort* __restrict__ Zl, const float* __restrict__ Zr,
    const int* __restrict__ adj, const int* __restrict__ offs,
    const int* __restrict__ cnt, const float* __restrict__ inv,
    const float* __restrict__ bias2, float* __restrict__ outF,
    ushort* __restrict__ outP, float* __restrict__ sums, int N) {
  constexpr int NPASS = 1 << NPLOG;
  constexpr int XCDG = 8 >> NPLOG;
  const int tid = threadIdx.x;
  const int xcd = blockIdx.x & 7;
  const int p = xcd & (NPASS - 1);
  const int setIdx = (blockIdx.x >> 3) * XCDG + (xcd >> NPLOG);
  const int nSets = (gridDim.x >> 3) * XCDG;
  const int lane = tid & 63;
  const int gb = lane & 56;
  const int k8 = lane & 7;
  const int sub = tid >> 3;          // 0..31
  const int c4 = (tid & 7) * 4;      // 0..28
  const int col = p * 32 + c4;
  const bool act = col < M;

  float ba0 = 0, ba1 = 0, ba2 = 0, ba3 = 0, bd0 = 0, bd1 = 0, bd2 = 0, bd3 = 0;
  if (act) {
    float4 ba = *(const float4*)&bias2[col];
    float4 bd = *(const float4*)&bias2[M + col];
    ba0 = ba.x; ba1 = ba.y; ba2 = ba.z; ba3 = ba.w;
    bd0 = bd.x; bd1 = bd.y; bd2 = bd.z; bd3 = bd.w;
  }
  float cs[4] = {0.f, 0.f, 0.f, 0.f}, cq[4] = {0.f, 0.f, 0.f, 0.f};
  const ushort* __restrict__ tab = Zl + (size_t)p * PSTRIDE + c4;
  const int kb = col >> 3, sl = col & 7;

  for (int n = setIdx * 32 + sub; n < N; n += nSets * 32) {
    int off = offs[n], deg = cnt[n];
    int pdeg = (deg + 7) & ~7;
    float s0 = 0.f, s1 = 0.f, s2 = 0.f, s3 = 0.f;
    // gather loop runs on ALL lanes (shfl-safe); inactive lanes read
    // in-bounds poison (finite) and discard below.
    for (int i = 0; i < pdeg; i += 8) GATHER8(tab, off + i);
    if (act) {
      float invn = inv[n];
      float4 zr = *(const float4*)&Zr[(size_t)n * M + col];
      float y0 = fmaf(s0, invn, zr.x + ba0);
      float y1 = fmaf(s1, invn, zr.y + ba1);
      float y2 = fmaf(s2, invn, zr.z + ba2);
      float y3 = fmaf(s3, invn, zr.w + ba3);
      if (deg > 0) { y0 += bd0; y1 += bd1; y2 += bd2; y3 += bd3; }
      if (RELU) {
        y0 = fmaxf(y0, 0.f); y1 = fmaxf(y1, 0.f);
        y2 = fmaxf(y2, 0.f); y3 = fmaxf(y3, 0.f);
      }
      if (PACK) {
        ushort4 H, L;
        H.x = bf16rne(y0); L.x = bf16rne(y0 - bf2f(H.x));
        H.y = bf16rne(y1); L.y = bf16rne(y1 - bf2f(H.y));
        H.z = bf16rne(y2); L.z = bf16rne(y2 - bf2f(H.z));
        H.w = bf16rne(y3); L.w = bf16rne(y3 - bf2f(H.w));
        size_t chunk = ((size_t)(kb * 2) * NP + n) * 8 + sl;
        *(ushort4*)&outP[chunk] = H;
        *(ushort4*)&outP[chunk + (size_t)NP * 8] = L;
      } else {
        *(float4*)&outF[(size_t)n * M + col] = make_float4(y0, y1, y2, y3);
      }
      if (STATS) {
        cs[0] += y0; cs[1] += y1; cs[2] += y2; cs[3] += y3;
        cq[0] += y0 * y0; cq[1] += y1 * y1; cq[2] += y2 * y2; cq[3] += y3 * y3;
      }
    }
  }
  if (STATS) {
    __shared__ float st1[32 * 32], st2[32 * 32];
#pragma unroll
    for (int j = 0; j < 4; ++j) {
      st1[sub * 32 + c4 + j] = cs[j];
      st2[sub * 32 + c4 + j] = cq[j];
    }
    __syncthreads();
    if (tid < 32) {
      float s1 = 0.f, s2 = 0.f;
#pragma unroll
      for (int t2 = 0; t2 < 32; ++t2) {
        s1 += st1[t2 * 32 + tid];
        s2 += st2[t2 * 32 + tid];
      }
      int c = p * 32 + tid;
      if (c < M) {
        atomicAdd(&sums[c], s1);
        atomicAdd(&sums[M + c], s2);
      }
    }
  }
}

__global__ void bn_affine(float* __restrict__ sums, const float* __restrict__ g,
                          const float* __restrict__ be, float* __restrict__ ab,
                          int M, float invN) {
  int j = threadIdx.x;
  if (j < M) {
    float s1 = sums[j], s2 = sums[M + j];
    float mu = s1 * invN;
    float var = fmaf(-mu, mu, s2 * invN);
    float a = g[j] / sqrtf(var + 1e-5f);
    ab[j] = a;
    ab[M + j] = fmaf(-mu, a, be[j]);
    sums[j] = 0.f;
    sums[M + j] = 0.f;
  }
}

extern "C" void kernel_launch(void* const* d_in, const int* in_sizes, int n_in,
                              void* d_out, int out_size, void* d_ws, size_t ws_size,
                              hipStream_t stream) {
  const int N = NN, E = NE;
  const float* x = (const float*)d_in[0];
  const int* ei = (const int*)d_in[1];
  const int* srcs = ei;
  const int* dsts = ei + E;

  const float* Wl1 = (const float*)d_in[2];
  const float* bl1 = (const float*)d_in[3];
  const float* Wr1 = (const float*)d_in[4];
  const float* Ws1 = (const float*)d_in[5];
  const float* bs1 = (const float*)d_in[6];
  const float* g1  = (const float*)d_in[7];
  const float* be1 = (const float*)d_in[8];
  const float* Wl2 = (const float*)d_in[9];
  const float* bl2 = (const float*)d_in[10];
  const float* Wr2 = (const float*)d_in[11];
  const float* Ws2 = (const float*)d_in[12];
  const float* bs2 = (const float*)d_in[13];
  const float* g2  = (const float*)d_in[14];
  const float* be2 = (const float*)d_in[15];
  const float* Wl3 = (const float*)d_in[16];
  const float* bl3 = (const float*)d_in[17];
  const float* Wr3 = (const float*)d_in[18];
  const float* Ws3 = (const float*)d_in[19];
  const float* bs3 = (const float*)d_in[20];
  const float* g3  = (const float*)d_in[21];
  const float* be3 = (const float*)d_in[22];
  const float* Wl4 = (const float*)d_in[23];
  const float* bl4 = (const float*)d_in[24];
  const float* Wr4 = (const float*)d_in[25];
  const float* Ws4 = (const float*)d_in[26];
  const float* bs4 = (const float*)d_in[27];

  // ---- workspace map (~121 MB) ----
  char* wsB = (char*)d_ws;
  ushort* hAP = (ushort*)wsB;
  ushort* hCP = hAP;
  ushort* xP  = (ushort*)(wsB + 51249152);
  ushort* hBP = xP;
  char* regC  = wsB + 51249152 + 25624576;
  ushort* aggP = (ushort*)regC;
  float* Zr   = (float*)regC;
  char* regD  = regC + 25624576;
  ushort* xb  = (ushort*)regD;
  ushort* Zl  = (ushort*)regD;
  char* p = regD + (size_t)NP * 128 * 2;
  ushort* W1p = (ushort*)p; p += 262144;
  ushort* W2p = (ushort*)p; p += 262144;
  ushort* W3p = (ushort*)p; p += 65536;
  ushort* W4p = (ushort*)p; p += 32768;
  float* sums = (float*)p; p += 512 * 4;
  float* ab   = (float*)p; p += 512 * 4;
  float* bias2 = (float*)p; p += 256 * 4;
  float* invc = (float*)p; p += (size_t)N * 4;
  int* cnt    = (int*)p; p += (size_t)N * 4;
  int* offs   = (int*)p; p += (size_t)N * 4;
  int* cursor = (int*)p; p += (size_t)N * 4;
  int* btot   = (int*)p; p += 256;
  int* adj    = (int*)p;   // NADJ ints (padded CSR)

  hipMemsetAsync(cnt, 0, sizeof(int) * N, stream);
  int eb = (E + 255) / 256;
  int nb = (N + 1023) / 1024;  // 49
  count_deg<<<eb, 256, 0, stream>>>(dsts, cnt, E);
  scan_block<<<nb, 1024, 0, stream>>>(cnt, offs, btot, N);
  scan_tops<<<1, 64, 0, stream>>>(btot, nb);
  finalize_csr<<<(N + 255) / 256, 256, 0, stream>>>(offs, btot, cnt, cursor, invc, N);
  fill_dummy<<<(NADJ + 255) / 256, 256, 0, stream>>>(adj, NADJ);
  fill_adj<<<eb, 256, 0, stream>>>(srcs, dsts, cursor, adj, E);

  pack_x<<<NP * 16 / 256, 256, 0, stream>>>(x, xP, xb, N);
  prep_w<1><<<32 * 256 / 256, 256, 0, stream>>>(Wl1, Wr1, Ws1, nullptr, W1p,
                                                256, 128, 256, 256, 256);

  const int RB = NP / 128;  // 391
  const int GP = 4096;      // pass-partitioned gather grid (multiple of 8)
  const float invN = 1.0f / (float)N;

  // L1: aggregate bf16(x) (4 XCD-passes), then [aggP|xP] @ W1p -> hAP
  aggregate1p<<<GP, 256, 0, stream>>>(xb, adj, offs, cnt, invc, aggP, sums, N);
  gemm_pk<1, 1, 8, 128><<<dim3(RB, 2), 256, 0, stream>>>(
      aggP, xP, W1p, bl1, bs1, nullptr, nullptr, hAP, sums, N, 256, 256, 256);
  bn_affine<<<1, 256, 0, stream>>>(sums, g1, be1, ab, 256, invN);

  // L2: Z = hA @ diag(a1)[Wl2|Wr2+Ws2] -> Zl blocked bf16 + Zr fp32; combine
  prep_w<0><<<32 * 256 / 256, 256, 0, stream>>>(Wl2, Wr2, Ws2, ab, W2p,
                                                256, 0, 128, 256, 256);
  prep_bias<<<128, 256, 0, stream>>>(Wl2, Wr2, Ws2, bl2, bs2, ab, bias2, 256, 128);
  gemm_pk<0, 0, 8, 0><<<dim3(RB, 2), 256, 0, stream>>>(
      hAP, nullptr, W2p, nullptr, nullptr, Zl, Zr, nullptr, nullptr, N, 128, 256, 256);
  combineP<2, 128, 1, 1, 1><<<GP, 256, 0, stream>>>(
      Zl, Zr, adj, offs, cnt, invc, bias2, nullptr, hBP, sums, N);
  bn_affine<<<1, 128, 0, stream>>>(sums, g2, be2, ab, 128, invN);

  // L3
  prep_w<0><<<16 * 128 / 256, 256, 0, stream>>>(Wl3, Wr3, Ws3, ab, W3p,
                                                128, 0, 64, 128, 128);
  prep_bias<<<64, 256, 0, stream>>>(Wl3, Wr3, Ws3, bl3, bs3, ab, bias2, 128, 64);
  gemm_pk<0, 0, 4, 0><<<dim3(RB, 1), 256, 0, stream>>>(
      hBP, nullptr, W3p, nullptr, nullptr, Zl, Zr, nullptr, nullptr, N, 64, 128, 128);
  combineP<1, 64, 1, 1, 1><<<GP, 256, 0, stream>>>(
      Zl, Zr, adj, offs, cnt, invc, bias2, nullptr, hCP, sums, N);
  bn_affine<<<1, 64, 0, stream>>>(sums, g3, be3, ab, 64, invN);

  // L4: Mp=80 (Mpad=128); 2 passes (cols 0-31, 32-39)
  prep_w<0><<<8 * 128 / 256, 256, 0, stream>>>(Wl4, Wr4, Ws4, ab, W4p,
                                               64, 0, 40, 80, 128);
  prep_bias<<<40, 256, 0, stream>>>(Wl4, Wr4, Ws4, bl4, bs4, ab, bias2, 64, 40);
  gemm_pk<0, 0, 2, 0><<<dim3(RB, 1), 256, 0, stream>>>(
      hCP, nullptr, W4p, nullptr, nullptr, Zl, Zr, nullptr, nullptr, N, 40, 80, 128);
  combineP<1, 40, 0, 0, 0><<<GP, 256, 0, stream>>>(
      Zl, Zr, adj, offs, cnt, invc, bias2, (float*)d_out, nullptr, nullptr, N);
}